// Round 1
// baseline (879.980 us; speedup 1.0000x reference)
//
#include <hip/hip_runtime.h>
#include <hip/hip_bf16.h>

#define DEV __device__ __forceinline__

// ---------- helpers ----------
DEV float bflo(unsigned u){ return __uint_as_float(u << 16); }
DEV float bfhi(unsigned u){ return __uint_as_float(u & 0xffff0000u); }
DEV float us2f(unsigned short u){ return __uint_as_float(((unsigned)u) << 16); }

DEV float gelu_tanh(float x){
  float x3 = x*x*x;
  float t = tanhf(0.7978845608028654f*(x + 0.044715f*x3));
  return 0.5f*x*(1.f + t);
}

// dims
#define SB 4096
#define NT 16384   // B*S
#define DM 64
#define NH 8
#define DH 8

// ---------- embedding + sinusoid pos emb ----------
__global__ __launch_bounds__(256) void embed_kernel(const int* __restrict__ x,
    const float* __restrict__ emb, float* __restrict__ h)
{
  int i = blockIdx.x*256 + threadIdx.x;        // 0 .. NT*64
  int t = i >> 6, d = i & 63;
  int s = t & (SB-1);
  int tok = x[t];
  float fe = (float)(d & ~1) * (1.0f/64.0f);
  float inv = expf(-9.210340371976184f * fe);  // 10000^{-fe}
  float ang = (float)s * inv;
  float pe = (d & 1) ? cosf(ang) : sinf(ang);
  h[i] = emb[tok*DM + d] + pe;
}

// ---------- layernorm: one wave per 64-wide row ----------
__global__ __launch_bounds__(256) void ln_kernel(const float* __restrict__ x,
    const float* __restrict__ s, const float* __restrict__ b, float* __restrict__ o)
{
  int lane = threadIdx.x & 63;
  int row = blockIdx.x*4 + (threadIdx.x >> 6);
  float v = x[(size_t)row*DM + lane];
  float sum = v;
  #pragma unroll
  for (int m=1; m<64; m<<=1) sum += __shfl_xor(sum, m, 64);
  float mean = sum * (1.f/64.f);
  float c = v - mean;
  float sq = c*c;
  #pragma unroll
  for (int m=1; m<64; m<<=1) sq += __shfl_xor(sq, m, 64);
  float inv = rsqrtf(sq*(1.f/64.f) + 1e-6f);
  o[(size_t)row*DM + lane] = c*inv*s[lane] + b[lane];
}

// ---------- register-tiled GEMM: C[M,N] = act((A[M,K]@W[K,N] + bias)*scale) [+C] ----------
// threads = 256 (16x16); BM = 16*TM, BN = 16*TN; K % 32 == 0
template<int BM,int BN,int TM,int TN,bool INB,bool OUTB,bool DOGELU,bool RES>
__global__ __launch_bounds__(256) void gemm_rt(
    const void* __restrict__ A,
    const float* __restrict__ W0,const float* __restrict__ W1,const float* __restrict__ W2,
    const float* __restrict__ B0,const float* __restrict__ B1,const float* __restrict__ B2,
    void* __restrict__ O0, void* __restrict__ O1, void* __restrict__ O2,
    int N, int K, float s0_, float s1_, float s2_)
{
  const int z = blockIdx.z;
  const float* W    = (z==0)?W0:((z==1)?W1:W2);
  const float* bias = (z==0)?B0:((z==1)?B1:B2);
  void* O           = (z==0)?O0:((z==1)?O1:O2);
  const float scale = (z==0)?s0_:((z==1)?s1_:s2_);

  __shared__ float sA[BM][36];
  __shared__ float sW[BN][36];
  const int tid = threadIdx.x;
  const int tx = tid & 15, ty = tid >> 4;
  const int row0 = blockIdx.x * BM, col0 = blockIdx.y * BN;

  float acc[TM][TN];
  #pragma unroll
  for (int i=0;i<TM;++i)
    #pragma unroll
    for (int j=0;j<TN;++j) acc[i][j] = 0.f;

  for (int kc = 0; kc < K; kc += 32) {
    // stage A chunk [BM][32]
    for (int e = tid*4; e < BM*32; e += 1024) {
      int r = e >> 5, kk = e & 31;
      float4 val;
      if constexpr (INB) {
        const unsigned short* Ab = (const unsigned short*)A;
        ushort4 u = *(const ushort4*)(Ab + (size_t)(row0 + r)*K + (kc + kk));
        val = make_float4(us2f(u.x), us2f(u.y), us2f(u.z), us2f(u.w));
      } else {
        const float* Af = (const float*)A;
        val = *(const float4*)(Af + (size_t)(row0 + r)*K + (kc + kk));
      }
      *(float4*)&sA[r][kk] = val;
    }
    // stage W chunk transposed: sW[c][kk] = W[kc+kk][col0+c]
    for (int e = tid*4; e < BN*32; e += 1024) {
      int c = e % BN, kk = e / BN;
      float4 wv = *(const float4*)(W + (size_t)(kc + kk)*N + (col0 + c));
      sW[c+0][kk] = wv.x; sW[c+1][kk] = wv.y; sW[c+2][kk] = wv.z; sW[c+3][kk] = wv.w;
    }
    __syncthreads();
    #pragma unroll
    for (int k4 = 0; k4 < 32; k4 += 4) {
      float4 a4[TM]; float4 w4[TN];
      #pragma unroll
      for (int rr=0; rr<TM; ++rr) a4[rr] = *(const float4*)&sA[ty + 16*rr][k4];
      #pragma unroll
      for (int cc=0; cc<TN; ++cc) w4[cc] = *(const float4*)&sW[tx + 16*cc][k4];
      #pragma unroll
      for (int rr=0; rr<TM; ++rr)
        #pragma unroll
        for (int cc=0; cc<TN; ++cc) {
          acc[rr][cc] = fmaf(a4[rr].x, w4[cc].x, acc[rr][cc]);
          acc[rr][cc] = fmaf(a4[rr].y, w4[cc].y, acc[rr][cc]);
          acc[rr][cc] = fmaf(a4[rr].z, w4[cc].z, acc[rr][cc]);
          acc[rr][cc] = fmaf(a4[rr].w, w4[cc].w, acc[rr][cc]);
        }
    }
    __syncthreads();
  }
  #pragma unroll
  for (int rr=0; rr<TM; ++rr) {
    int r = row0 + ty + 16*rr;
    #pragma unroll
    for (int cc=0; cc<TN; ++cc) {
      int c = col0 + tx + 16*cc;
      float val = (acc[rr][cc] + bias[c]) * scale;
      if constexpr (DOGELU) val = gelu_tanh(val);
      size_t oi = (size_t)r*N + c;
      if constexpr (OUTB) {
        ((__hip_bfloat16*)O)[oi] = __float2bfloat16(val);
      } else {
        float* Of = (float*)O;
        if constexpr (RES) val += Of[oi];
        Of[oi] = val;
      }
    }
  }
}

// ---------- sliding-window attention ----------
// grid (S/256, B*H), 128 threads; thread t handles queries 2t, 2t+1 of its tile.
// K/V staged bf16, transposed [d][key]; no max-subtraction (scores provably small).
__global__ __launch_bounds__(128) void attn_kernel(const float* __restrict__ q,
    const float* __restrict__ k, const float* __restrict__ v, float* __restrict__ out)
{
  int qt = blockIdx.x, bh = blockIdx.y;
  int b = bh >> 3, hh = bh & 7;
  int t = threadIdx.x;
  int qbase = qt << 8;
  int kbase = qbase - 256;

  __shared__ __hip_bfloat16 kT[8][776];
  __shared__ __hip_bfloat16 vT[8][776];

  const float* kb_ = k + ((size_t)b*SB)*DM + hh*DH;
  const float* vb_ = v + ((size_t)b*SB)*DM + hh*DH;

  for (int e = t; e < 6144; e += 128) {   // 768 keys x 8 dims
    int j = e >> 3, d = e & 7;
    int g = kbase + j;
    float kv = 0.f, vv = 0.f;
    if ((unsigned)g < (unsigned)SB) {
      kv = kb_[(size_t)g*DM + d];
      vv = vb_[(size_t)g*DM + d];
    }
    kT[d][j] = __float2bfloat16(kv);
    vT[d][j] = __float2bfloat16(vv);
  }
  __syncthreads();

  int q0g = qbase + 2*t;
  const float* qp = q + ((size_t)b*SB + q0g)*DM + hh*DH;
  float4 qa = *(const float4*)qp,        qb4 = *(const float4*)(qp+4);
  float4 qc = *(const float4*)(qp+DM),   qd  = *(const float4*)(qp+DM+4);
  float q0f[8] = {qa.x,qa.y,qa.z,qa.w,qb4.x,qb4.y,qb4.z,qb4.w};
  float q1f[8] = {qc.x,qc.y,qc.z,qc.w,qd.x,qd.y,qd.z,qd.w};

  float o0[8], o1[8];
  #pragma unroll
  for (int d=0; d<8; ++d){ o0[d]=0.f; o1[d]=0.f; }
  float l0 = 0.f, l1 = 0.f;
  int A0 = (2*t) & ~3;
  int lo0 = 2*t;

  for (int m = 0; m < 129; ++m) {
    int idx0 = A0 + 4*m;
    uint2 kp[8], vp[8];
    #pragma unroll
    for (int d=0; d<8; ++d) kp[d] = *(const uint2*)&kT[d][idx0];
    #pragma unroll
    for (int d=0; d<8; ++d) vp[d] = *(const uint2*)&vT[d][idx0];
    #pragma unroll
    for (int sub=0; sub<4; ++sub) {
      int idx = idx0 + sub;
      float kf[8];
      #pragma unroll
      for (int d=0; d<8; ++d) {
        unsigned u = (sub & 2) ? kp[d].y : kp[d].x;
        kf[d] = (sub & 1) ? bfhi(u) : bflo(u);
      }
      float s0 = 0.f, s1 = 0.f;
      #pragma unroll
      for (int d=0; d<8; ++d) { s0 = fmaf(q0f[d], kf[d], s0); s1 = fmaf(q1f[d], kf[d], s1); }
      int g = kbase + idx;
      bool gok = (unsigned)g < (unsigned)SB;
      int rel = idx - lo0;
      bool ok0 = gok && (rel >= 0) && (rel <= 512);
      bool ok1 = gok && (rel >= 1) && (rel <= 513);
      float p0 = ok0 ? __expf(s0) : 0.f;
      float p1 = ok1 ? __expf(s1) : 0.f;
      l0 += p0; l1 += p1;
      #pragma unroll
      for (int d=0; d<8; ++d) {
        unsigned u = (sub & 2) ? vp[d].y : vp[d].x;
        float vf = (sub & 1) ? bfhi(u) : bflo(u);
        o0[d] = fmaf(p0, vf, o0[d]);
        o1[d] = fmaf(p1, vf, o1[d]);
      }
    }
  }
  float r0 = 1.f/l0, r1 = 1.f/l1;
  float* op = out + ((size_t)b*SB + q0g)*DM + hh*DH;
  *(float4*)(op)      = make_float4(o0[0]*r0, o0[1]*r0, o0[2]*r0, o0[3]*r0);
  *(float4*)(op+4)    = make_float4(o0[4]*r0, o0[5]*r0, o0[6]*r0, o0[7]*r0);
  *(float4*)(op+DM)   = make_float4(o1[0]*r1, o1[1]*r1, o1[2]*r1, o1[3]*r1);
  *(float4*)(op+DM+4) = make_float4(o1[4]*r1, o1[5]*r1, o1[6]*r1, o1[7]*r1);
}

// ---------- mean-pool partials + classifier ----------
__global__ __launch_bounds__(256) void pool_partial(const float* __restrict__ a, float* __restrict__ part)
{
  int b = blockIdx.x, sb = blockIdx.y;     // grid (4,16)
  int d = threadIdx.x & 63, seg = threadIdx.x >> 6;
  const float* base = a + ((size_t)(b*SB + sb*256 + seg*64))*DM + d;
  float sum = 0.f;
  #pragma unroll 4
  for (int i = 0; i < 64; ++i) sum += base[(size_t)i*DM];
  __shared__ float red[4][64];
  red[seg][d] = sum;
  __syncthreads();
  if (threadIdx.x < 64)
    part[(b*16 + sb)*64 + threadIdx.x] =
        red[0][threadIdx.x]+red[1][threadIdx.x]+red[2][threadIdx.x]+red[3][threadIdx.x];
}

__global__ __launch_bounds__(256) void pool_finalize(const float* __restrict__ part,
    const float* __restrict__ wcls, const float* __restrict__ bcls, float* __restrict__ out)
{
  int tid = threadIdx.x;
  int b = tid >> 6, d = tid & 63;
  float sum = 0.f;
  #pragma unroll
  for (int sb = 0; sb < 16; ++sb) sum += part[(b*16+sb)*64 + d];
  __shared__ float pooled[4][64];
  pooled[b][d] = sum * (1.f/4096.f);
  __syncthreads();
  if (tid < 40) {
    int bb = tid / 10, c = tid % 10;
    float acc = bcls[c];
    #pragma unroll
    for (int dd = 0; dd < 64; ++dd) acc = fmaf(pooled[bb][dd], wcls[dd*10 + c], acc);
    out[tid] = acc;
  }
}

// ---------- launcher ----------
extern "C" void kernel_launch(void* const* d_in, const int* in_sizes, int n_in,
                              void* d_out, int out_size, void* d_ws, size_t ws_size,
                              hipStream_t stream)
{
  const int*   x    = (const int*)d_in[0];
  const float* emb  = (const float*)d_in[1];
  const float* wq   = (const float*)d_in[2];
  const float* bq   = (const float*)d_in[3];
  const float* wk   = (const float*)d_in[4];
  const float* bk   = (const float*)d_in[5];
  const float* wv   = (const float*)d_in[6];
  const float* bv   = (const float*)d_in[7];
  const float* wo   = (const float*)d_in[8];
  const float* bo   = (const float*)d_in[9];
  const float* ln1s = (const float*)d_in[10];
  const float* ln1b = (const float*)d_in[11];
  const float* ln2s = (const float*)d_in[12];
  const float* ln2b = (const float*)d_in[13];
  const float* w1   = (const float*)d_in[14];
  const float* b1   = (const float*)d_in[15];
  const float* w2   = (const float*)d_in[16];
  const float* b2   = (const float*)d_in[17];
  const float* lnfs = (const float*)d_in[18];
  const float* lnfb = (const float*)d_in[19];
  const float* wcls = (const float*)d_in[20];
  const float* bcls = (const float*)d_in[21];
  float* out = (float*)d_out;

  float* ws = (float*)d_ws;
  float* h  = ws;
  float* a  = ws + (1u<<20);
  float* qb = ws + 2u*(1u<<20);
  float* kb = ws + 3u*(1u<<20);
  float* vb = ws + 4u*(1u<<20);
  __hip_bfloat16* mid = (__hip_bfloat16*)(ws + 5u*(1u<<20));   // 16384x512 bf16
  float* part = ws + 9u*(1u<<20) + (1u<<18);                   // after mid (4M float-slots)

  embed_kernel<<<4096,256,0,stream>>>(x, emb, h);
  const float qscale = 0.35355339059327373f;  // 1/sqrt(8)

  for (int l = 0; l < 4; ++l) {
    ln_kernel<<<4096,256,0,stream>>>(h, ln1s+64*l, ln1b+64*l, a);
    gemm_rt<128,64,8,4,false,false,false,false><<<dim3(128,1,3),256,0,stream>>>(
        a, wq+4096*l, wk+4096*l, wv+4096*l, bq+64*l, bk+64*l, bv+64*l,
        qb, kb, vb, 64, 64, qscale, 1.f, 1.f);
    attn_kernel<<<dim3(16,32),128,0,stream>>>(qb, kb, vb, a);
    gemm_rt<128,64,8,4,false,false,false,true><<<dim3(128,1,1),256,0,stream>>>(
        a, wo+4096*l, wo+4096*l, wo+4096*l, bo+64*l, bo+64*l, bo+64*l,
        h, h, h, 64, 64, 1.f, 1.f, 1.f);
    ln_kernel<<<4096,256,0,stream>>>(h, ln2s+64*l, ln2b+64*l, a);
    gemm_rt<128,64,8,4,false,true,true,false><<<dim3(128,8,1),256,0,stream>>>(
        a, w1+32768*l, w1+32768*l, w1+32768*l, b1+512*l, b1+512*l, b1+512*l,
        mid, mid, mid, 512, 64, 1.f, 1.f, 1.f);
    gemm_rt<64,64,4,4,true,false,false,true><<<dim3(256,1,1),256,0,stream>>>(
        mid, w2+32768*l, w2+32768*l, w2+32768*l, b2+64*l, b2+64*l, b2+64*l,
        h, h, h, 64, 512, 1.f, 1.f, 1.f);
  }
  ln_kernel<<<4096,256,0,stream>>>(h, lnfs, lnfb, a);
  pool_partial<<<dim3(4,16),256,0,stream>>>(a, part);
  pool_finalize<<<1,256,0,stream>>>(part, wcls, bcls, out);
}

// Round 2
// 621.501 us; speedup vs baseline: 1.4159x; 1.4159x over previous
//
#include <hip/hip_runtime.h>
#include <hip/hip_bf16.h>

#define DEV __device__ __forceinline__

// ---------- helpers ----------
DEV float us2f(unsigned short u){ return __uint_as_float(((unsigned)u) << 16); }

DEV float gelu_tanh(float x){
  float x3 = x*x*x;
  float t = tanhf(0.7978845608028654f*(x + 0.044715f*x3));
  return 0.5f*x*(1.f + t);
}

// dims
#define SB 4096
#define NT 16384   // B*S
#define DM 64
#define NH 8
#define DH 8

// ---------- embedding + sinusoid pos emb ----------
__global__ __launch_bounds__(256) void embed_kernel(const int* __restrict__ x,
    const float* __restrict__ emb, float* __restrict__ h)
{
  int i = blockIdx.x*256 + threadIdx.x;        // 0 .. NT*64
  int t = i >> 6, d = i & 63;
  int s = t & (SB-1);
  int tok = x[t];
  float fe = (float)(d & ~1) * (1.0f/64.0f);
  float inv = expf(-9.210340371976184f * fe);  // 10000^{-fe}
  float ang = (float)s * inv;
  float pe = (d & 1) ? cosf(ang) : sinf(ang);
  h[i] = emb[tok*DM + d] + pe;
}

// ---------- layernorm: one wave per 64-wide row ----------
__global__ __launch_bounds__(256) void ln_kernel(const float* __restrict__ x,
    const float* __restrict__ s, const float* __restrict__ b, float* __restrict__ o)
{
  int lane = threadIdx.x & 63;
  int row = blockIdx.x*4 + (threadIdx.x >> 6);
  float v = x[(size_t)row*DM + lane];
  float sum = v;
  #pragma unroll
  for (int m=1; m<64; m<<=1) sum += __shfl_xor(sum, m, 64);
  float mean = sum * (1.f/64.f);
  float c = v - mean;
  float sq = c*c;
  #pragma unroll
  for (int m=1; m<64; m<<=1) sq += __shfl_xor(sq, m, 64);
  float inv = rsqrtf(sq*(1.f/64.f) + 1e-6f);
  o[(size_t)row*DM + lane] = c*inv*s[lane] + b[lane];
}

// ---------- register-tiled GEMM: C[M,N] = act((A[M,K]@W[K,N] + bias)*scale) [+C] ----------
// threads = 256 (16x16); BM = 16*TM, BN = 16*TN; K % 32 == 0
template<int BM,int BN,int TM,int TN,bool INB,bool OUTB,bool DOGELU,bool RES>
__global__ __launch_bounds__(256) void gemm_rt(
    const void* __restrict__ A,
    const float* __restrict__ W0,const float* __restrict__ W1,const float* __restrict__ W2,
    const float* __restrict__ B0,const float* __restrict__ B1,const float* __restrict__ B2,
    void* __restrict__ O0, void* __restrict__ O1, void* __restrict__ O2,
    int N, int K, float s0_, float s1_, float s2_)
{
  const int z = blockIdx.z;
  const float* W    = (z==0)?W0:((z==1)?W1:W2);
  const float* bias = (z==0)?B0:((z==1)?B1:B2);
  void* O           = (z==0)?O0:((z==1)?O1:O2);
  const float scale = (z==0)?s0_:((z==1)?s1_:s2_);

  __shared__ float sA[BM][36];
  __shared__ float sW[BN][36];
  const int tid = threadIdx.x;
  const int tx = tid & 15, ty = tid >> 4;
  const int row0 = blockIdx.x * BM, col0 = blockIdx.y * BN;

  float acc[TM][TN];
  #pragma unroll
  for (int i=0;i<TM;++i)
    #pragma unroll
    for (int j=0;j<TN;++j) acc[i][j] = 0.f;

  for (int kc = 0; kc < K; kc += 32) {
    // stage A chunk [BM][32]
    for (int e = tid*4; e < BM*32; e += 1024) {
      int r = e >> 5, kk = e & 31;
      float4 val;
      if constexpr (INB) {
        const unsigned short* Ab = (const unsigned short*)A;
        ushort4 u = *(const ushort4*)(Ab + (size_t)(row0 + r)*K + (kc + kk));
        val = make_float4(us2f(u.x), us2f(u.y), us2f(u.z), us2f(u.w));
      } else {
        const float* Af = (const float*)A;
        val = *(const float4*)(Af + (size_t)(row0 + r)*K + (kc + kk));
      }
      *(float4*)&sA[r][kk] = val;
    }
    // stage W chunk transposed: sW[c][kk] = W[kc+kk][col0+c]
    for (int e = tid*4; e < BN*32; e += 1024) {
      int c = e % BN, kk = e / BN;
      float4 wv = *(const float4*)(W + (size_t)(kc + kk)*N + (col0 + c));
      sW[c+0][kk] = wv.x; sW[c+1][kk] = wv.y; sW[c+2][kk] = wv.z; sW[c+3][kk] = wv.w;
    }
    __syncthreads();
    #pragma unroll
    for (int k4 = 0; k4 < 32; k4 += 4) {
      float4 a4[TM]; float4 w4[TN];
      #pragma unroll
      for (int rr=0; rr<TM; ++rr) a4[rr] = *(const float4*)&sA[ty + 16*rr][k4];
      #pragma unroll
      for (int cc=0; cc<TN; ++cc) w4[cc] = *(const float4*)&sW[tx + 16*cc][k4];
      #pragma unroll
      for (int rr=0; rr<TM; ++rr)
        #pragma unroll
        for (int cc=0; cc<TN; ++cc) {
          acc[rr][cc] = fmaf(a4[rr].x, w4[cc].x, acc[rr][cc]);
          acc[rr][cc] = fmaf(a4[rr].y, w4[cc].y, acc[rr][cc]);
          acc[rr][cc] = fmaf(a4[rr].z, w4[cc].z, acc[rr][cc]);
          acc[rr][cc] = fmaf(a4[rr].w, w4[cc].w, acc[rr][cc]);
        }
    }
    __syncthreads();
  }
  #pragma unroll
  for (int rr=0; rr<TM; ++rr) {
    int r = row0 + ty + 16*rr;
    #pragma unroll
    for (int cc=0; cc<TN; ++cc) {
      int c = col0 + tx + 16*cc;
      float val = (acc[rr][cc] + bias[c]) * scale;
      if constexpr (DOGELU) val = gelu_tanh(val);
      size_t oi = (size_t)r*N + c;
      if constexpr (OUTB) {
        ((__hip_bfloat16*)O)[oi] = __float2bfloat16(val);
      } else {
        float* Of = (float*)O;
        if constexpr (RES) val += Of[oi];
        Of[oi] = val;
      }
    }
  }
}

// ---------- sliding-window attention v2 ----------
// grid (16, 32): 256 queries per block, 256 threads.
// thread t: qg = t>>2 owns queries 4qg..4qg+3; chunk c = t&3 covers rel = 4qg+c+4i.
// K/V staged f32 transposed [dim_pair][key]; maskless softmax (scores provably small),
// chunk partials combine exactly via shfl_xor.
__global__ __launch_bounds__(256) void attn_kernel(const float* __restrict__ q,
    const float* __restrict__ k, const float* __restrict__ v, float* __restrict__ out)
{
  const int qt = blockIdx.x, bh = blockIdx.y;
  const int b = bh >> 3, hh = bh & 7;
  const int t = threadIdx.x;
  const int q0 = qt << 8;
  const int kbase = q0 - 256;

  __shared__ float2 sK[4][768];
  __shared__ float2 sV[4][768];

  const float* kb_ = k + ((size_t)b*SB)*DM + hh*DH;
  const float* vb_ = v + ((size_t)b*SB)*DM + hh*DH;

  // stage window: 768 keys x 8 dims, f32
  for (int e = t; e < 1536; e += 256) {
    int rel = e >> 1, dq = e & 1;
    int g = kbase + rel;
    float4 kv = make_float4(0.f,0.f,0.f,0.f), vv = make_float4(0.f,0.f,0.f,0.f);
    if ((unsigned)g < (unsigned)SB) {
      kv = *(const float4*)(kb_ + (size_t)g*DM + 4*dq);
      vv = *(const float4*)(vb_ + (size_t)g*DM + 4*dq);
    }
    sK[2*dq+0][rel] = make_float2(kv.x, kv.y);
    sK[2*dq+1][rel] = make_float2(kv.z, kv.w);
    sV[2*dq+0][rel] = make_float2(vv.x, vv.y);
    sV[2*dq+1][rel] = make_float2(vv.z, vv.w);
  }
  __syncthreads();

  const int qg = t >> 2;
  const int c  = t & 3;
  const int qa = q0 + 4*qg;

  float qf[4][8];
  #pragma unroll
  for (int j = 0; j < 4; ++j) {
    const float* qp = q + ((size_t)b*SB + qa + j)*DM + hh*DH;
    float4 x0 = *(const float4*)qp;
    float4 x1 = *(const float4*)(qp+4);
    qf[j][0]=x0.x; qf[j][1]=x0.y; qf[j][2]=x0.z; qf[j][3]=x0.w;
    qf[j][4]=x1.x; qf[j][5]=x1.y; qf[j][6]=x1.z; qf[j][7]=x1.w;
  }

  float o[4][8];
  float l[4] = {0.f,0.f,0.f,0.f};
  #pragma unroll
  for (int j=0;j<4;++j)
    #pragma unroll
    for (int d=0;d<8;++d) o[j][d]=0.f;

  int rel = 4*qg + c;
  for (int i = 0; i < 129; ++i, rel += 4) {
    float2 k0 = sK[0][rel], k1 = sK[1][rel], k2 = sK[2][rel], k3 = sK[3][rel];
    float2 v0 = sV[0][rel], v1 = sV[1][rel], v2 = sV[2][rel], v3 = sV[3][rel];
    float kf[8] = {k0.x,k0.y,k1.x,k1.y,k2.x,k2.y,k3.x,k3.y};
    float vf[8] = {v0.x,v0.y,v1.x,v1.y,v2.x,v2.y,v3.x,v3.y};
    int g = kbase + rel;
    bool gok = (unsigned)g < (unsigned)SB;
    int t0 = c + 4*i;                    // rel - 4qg
    #pragma unroll
    for (int j = 0; j < 4; ++j) {
      float s = 0.f;
      #pragma unroll
      for (int d = 0; d < 8; ++d) s = fmaf(qf[j][d], kf[d], s);
      bool ok = gok && ((unsigned)(t0 - j) <= 512u);
      float p = ok ? __expf(s) : 0.f;
      l[j] += p;
      #pragma unroll
      for (int d = 0; d < 8; ++d) o[j][d] = fmaf(p, vf[d], o[j][d]);
    }
  }

  // combine chunk partials across the 4 lanes of each query group (exact: no max-sub)
  #pragma unroll
  for (int j = 0; j < 4; ++j) {
    l[j] += __shfl_xor(l[j], 1, 64);
    l[j] += __shfl_xor(l[j], 2, 64);
    #pragma unroll
    for (int d = 0; d < 8; ++d) {
      o[j][d] += __shfl_xor(o[j][d], 1, 64);
      o[j][d] += __shfl_xor(o[j][d], 2, 64);
    }
  }
  if (c == 0) {
    #pragma unroll
    for (int j = 0; j < 4; ++j) {
      float r = 1.f / l[j];
      float* op = out + ((size_t)b*SB + qa + j)*DM + hh*DH;
      *(float4*)(op)   = make_float4(o[j][0]*r, o[j][1]*r, o[j][2]*r, o[j][3]*r);
      *(float4*)(op+4) = make_float4(o[j][4]*r, o[j][5]*r, o[j][6]*r, o[j][7]*r);
    }
  }
}

// ---------- mean-pool partials + classifier ----------
__global__ __launch_bounds__(256) void pool_partial(const float* __restrict__ a, float* __restrict__ part)
{
  int b = blockIdx.x, sb = blockIdx.y;     // grid (4,16)
  int d = threadIdx.x & 63, seg = threadIdx.x >> 6;
  const float* base = a + ((size_t)(b*SB + sb*256 + seg*64))*DM + d;
  float sum = 0.f;
  #pragma unroll 4
  for (int i = 0; i < 64; ++i) sum += base[(size_t)i*DM];
  __shared__ float red[4][64];
  red[seg][d] = sum;
  __syncthreads();
  if (threadIdx.x < 64)
    part[(b*16 + sb)*64 + threadIdx.x] =
        red[0][threadIdx.x]+red[1][threadIdx.x]+red[2][threadIdx.x]+red[3][threadIdx.x];
}

__global__ __launch_bounds__(256) void pool_finalize(const float* __restrict__ part,
    const float* __restrict__ wcls, const float* __restrict__ bcls, float* __restrict__ out)
{
  int tid = threadIdx.x;
  int b = tid >> 6, d = tid & 63;
  float sum = 0.f;
  #pragma unroll
  for (int sb = 0; sb < 16; ++sb) sum += part[(b*16+sb)*64 + d];
  __shared__ float pooled[4][64];
  pooled[b][d] = sum * (1.f/4096.f);
  __syncthreads();
  if (tid < 40) {
    int bb = tid / 10, c = tid % 10;
    float acc = bcls[c];
    #pragma unroll
    for (int dd = 0; dd < 64; ++dd) acc = fmaf(pooled[bb][dd], wcls[dd*10 + c], acc);
    out[tid] = acc;
  }
}

// ---------- launcher ----------
extern "C" void kernel_launch(void* const* d_in, const int* in_sizes, int n_in,
                              void* d_out, int out_size, void* d_ws, size_t ws_size,
                              hipStream_t stream)
{
  const int*   x    = (const int*)d_in[0];
  const float* emb  = (const float*)d_in[1];
  const float* wq   = (const float*)d_in[2];
  const float* bq   = (const float*)d_in[3];
  const float* wk   = (const float*)d_in[4];
  const float* bk   = (const float*)d_in[5];
  const float* wv   = (const float*)d_in[6];
  const float* bv   = (const float*)d_in[7];
  const float* wo   = (const float*)d_in[8];
  const float* bo   = (const float*)d_in[9];
  const float* ln1s = (const float*)d_in[10];
  const float* ln1b = (const float*)d_in[11];
  const float* ln2s = (const float*)d_in[12];
  const float* ln2b = (const float*)d_in[13];
  const float* w1   = (const float*)d_in[14];
  const float* b1   = (const float*)d_in[15];
  const float* w2   = (const float*)d_in[16];
  const float* b2   = (const float*)d_in[17];
  const float* lnfs = (const float*)d_in[18];
  const float* lnfb = (const float*)d_in[19];
  const float* wcls = (const float*)d_in[20];
  const float* bcls = (const float*)d_in[21];
  float* out = (float*)d_out;

  float* ws = (float*)d_ws;
  float* h  = ws;
  float* a  = ws + (1u<<20);
  float* qb = ws + 2u*(1u<<20);
  float* kb = ws + 3u*(1u<<20);
  float* vb = ws + 4u*(1u<<20);
  __hip_bfloat16* mid = (__hip_bfloat16*)(ws + 5u*(1u<<20));   // 16384x512 bf16
  float* part = ws + 9u*(1u<<20) + (1u<<18);                   // after mid (4M float-slots)

  embed_kernel<<<4096,256,0,stream>>>(x, emb, h);
  const float qscale = 0.35355339059327373f;  // 1/sqrt(8)

  for (int l = 0; l < 4; ++l) {
    ln_kernel<<<4096,256,0,stream>>>(h, ln1s+64*l, ln1b+64*l, a);
    gemm_rt<128,64,8,4,false,false,false,false><<<dim3(128,1,3),256,0,stream>>>(
        a, wq+4096*l, wk+4096*l, wv+4096*l, bq+64*l, bk+64*l, bv+64*l,
        qb, kb, vb, 64, 64, qscale, 1.f, 1.f);
    attn_kernel<<<dim3(16,32),256,0,stream>>>(qb, kb, vb, a);
    gemm_rt<128,64,8,4,false,false,false,true><<<dim3(128,1,1),256,0,stream>>>(
        a, wo+4096*l, wo+4096*l, wo+4096*l, bo+64*l, bo+64*l, bo+64*l,
        h, h, h, 64, 64, 1.f, 1.f, 1.f);
    ln_kernel<<<4096,256,0,stream>>>(h, ln2s+64*l, ln2b+64*l, a);
    gemm_rt<128,64,8,4,false,true,true,false><<<dim3(128,8,1),256,0,stream>>>(
        a, w1+32768*l, w1+32768*l, w1+32768*l, b1+512*l, b1+512*l, b1+512*l,
        mid, mid, mid, 512, 64, 1.f, 1.f, 1.f);
    gemm_rt<64,64,4,4,true,false,false,true><<<dim3(256,1,1),256,0,stream>>>(
        mid, w2+32768*l, w2+32768*l, w2+32768*l, b2+64*l, b2+64*l, b2+64*l,
        h, h, h, 64, 512, 1.f, 1.f, 1.f);
  }
  ln_kernel<<<4096,256,0,stream>>>(h, lnfs, lnfb, a);
  pool_partial<<<dim3(4,16),256,0,stream>>>(a, part);
  pool_finalize<<<1,256,0,stream>>>(part, wcls, bcls, out);
}

// Round 3
// 393.638 us; speedup vs baseline: 2.2355x; 1.5789x over previous
//
#include <hip/hip_runtime.h>
#include <hip/hip_bf16.h>

#define DEV __device__ __forceinline__

typedef __attribute__((ext_vector_type(8))) short bf16x8;
typedef __attribute__((ext_vector_type(4))) float f32x4;

// ---------- helpers ----------
DEV short f2bf(float x){ __hip_bfloat16 h = __float2bfloat16(x); return *(short*)&h; }

DEV float gelu_tanh(float x){
  float x3 = x*x*x;
  float t = tanhf(0.7978845608028654f*(x + 0.044715f*x3));
  return 0.5f*x*(1.f + t);
}

// dims
#define SB 4096
#define NT 16384   // B*S
#define DM 64
#define NH 8
#define DH 8

// ---------- embedding + sinusoid pos emb ----------
__global__ __launch_bounds__(256) void embed_kernel(const int* __restrict__ x,
    const float* __restrict__ emb, float* __restrict__ h)
{
  int i = blockIdx.x*256 + threadIdx.x;        // 0 .. NT*64
  int t = i >> 6, d = i & 63;
  int s = t & (SB-1);
  int tok = x[t];
  float fe = (float)(d & ~1) * (1.0f/64.0f);
  float inv = expf(-9.210340371976184f * fe);  // 10000^{-fe}
  float ang = (float)s * inv;
  float pe = (d & 1) ? cosf(ang) : sinf(ang);
  h[i] = emb[tok*DM + d] + pe;
}

// ---------- layernorm (final only): one wave per 64-wide row ----------
__global__ __launch_bounds__(256) void ln_kernel(const float* __restrict__ x,
    const float* __restrict__ s, const float* __restrict__ b, float* __restrict__ o)
{
  int lane = threadIdx.x & 63;
  int row = blockIdx.x*4 + (threadIdx.x >> 6);
  float v = x[(size_t)row*DM + lane];
  float sum = v;
  #pragma unroll
  for (int m=1; m<64; m<<=1) sum += __shfl_xor(sum, m, 64);
  float mean = sum * (1.f/64.f);
  float c = v - mean;
  float sq = c*c;
  #pragma unroll
  for (int m=1; m<64; m<<=1) sq += __shfl_xor(sq, m, 64);
  float inv = rsqrtf(sq*(1.f/64.f) + 1e-6f);
  o[(size_t)row*DM + lane] = c*inv*s[lane] + b[lane];
}

// ---------- weight convert+transpose: f32 [K][N] -> bf16 [N][K], 32x32 tiles ----------
__global__ __launch_bounds__(256) void wconv(
    const float* __restrict__ wq, const float* __restrict__ wk,
    const float* __restrict__ wv, const float* __restrict__ wo,
    const float* __restrict__ w1, const float* __restrict__ w2,
    short* __restrict__ wqT, short* __restrict__ wkT,
    short* __restrict__ wvT, short* __restrict__ woT,
    short* __restrict__ w1T, short* __restrict__ w2T)
{
  int t = blockIdx.x, l = blockIdx.y;
  const float* src; short* dst; int K, N, kt, nt;
  if (t < 16) {
    int m = t >> 2, sub = t & 3; kt = sub >> 1; nt = sub & 1; K = 64; N = 64;
    const float* s4[4] = {wq, wk, wv, wo};
    short*       d4[4] = {wqT, wkT, wvT, woT};
    src = s4[m] + l*4096; dst = d4[m] + l*4096;
  } else if (t < 48) {
    kt = (t-16) >> 4; nt = (t-16) & 15; K = 64; N = 512;
    src = w1 + l*32768; dst = w1T + l*32768;
  } else {
    kt = (t-48) >> 1; nt = (t-48) & 1; K = 512; N = 64;
    src = w2 + l*32768; dst = w2T + l*32768;
  }
  __shared__ float lds[32][33];
  int tx = threadIdx.x & 31, ty = threadIdx.x >> 5;
  int k0 = kt*32, n0 = nt*32;
  #pragma unroll
  for (int j=0;j<4;++j) lds[ty+8*j][tx] = src[(size_t)(k0+ty+8*j)*N + n0 + tx];
  __syncthreads();
  #pragma unroll
  for (int j=0;j<4;++j) {
    int nn = ty+8*j;
    dst[(size_t)(n0+nn)*K + k0 + tx] = f2bf(lds[tx][nn]);
  }
}

// ---------- MFMA GEMM: O = act((A @ W + bias)*scale) [+O] ----------
// block = 256 (4 waves); wave computes 16 rows x CT*16 cols. K = KSTEPS*32.
// A: LNF ? f32 [M][64] (layernorm fused) : bf16 [M][K].  WT: bf16 [N][K] (transposed).
// A/B fragments loaded straight from global (L2-resident), no LDS.
template<int CT, int KSTEPS, bool LNF, bool OUTB, bool DOGELU, bool RES>
__global__ __launch_bounds__(256) void gemm_mfma(
    const void* __restrict__ Ap,
    const float* __restrict__ lns, const float* __restrict__ lnb,
    const short* __restrict__ WT0, const short* __restrict__ WT1, const short* __restrict__ WT2,
    const float* __restrict__ B0, const float* __restrict__ B1, const float* __restrict__ B2,
    void* __restrict__ O0, void* __restrict__ O1, void* __restrict__ O2,
    int N, float s0_, float s1_, float s2_)
{
  constexpr int K = KSTEPS*32;
  static_assert(!LNF || KSTEPS == 2, "LN fusion requires K==64");
  const int z = blockIdx.z;
  const short* WT   = z==0?WT0:(z==1?WT1:WT2);
  const float* bias = z==0?B0:(z==1?B1:B2);
  void* O           = z==0?O0:(z==1?O1:O2);
  const float scale = z==0?s0_:(z==1?s1_:s2_);

  const int lane = threadIdx.x & 63;
  const int wv = threadIdx.x >> 6;
  const int r = lane & 15, kq = lane >> 4;         // kq = k-quarter
  const int row = blockIdx.x*64 + wv*16 + r;       // A row this lane loads
  const int col0 = blockIdx.y * (CT*16);

  f32x4 acc[CT];
  #pragma unroll
  for (int c=0;c<CT;++c) acc[c] = (f32x4){0.f,0.f,0.f,0.f};

  bf16x8 afr[KSTEPS];
  if constexpr (LNF) {
    const float* hrow = (const float*)Ap + (size_t)row*64 + kq*8;
    float4 u0 = *(const float4*)(hrow);
    float4 u1 = *(const float4*)(hrow+4);
    float4 u2 = *(const float4*)(hrow+32);
    float4 u3 = *(const float4*)(hrow+36);
    const float* sp = lns + kq*8;
    float4 sv0 = *(const float4*)(sp), sv1 = *(const float4*)(sp+4);
    float4 sv2 = *(const float4*)(sp+32), sv3 = *(const float4*)(sp+36);
    const float* bp = lnb + kq*8;
    float4 bv0 = *(const float4*)(bp), bv1 = *(const float4*)(bp+4);
    float4 bv2 = *(const float4*)(bp+32), bv3 = *(const float4*)(bp+36);
    float xs[16] = {u0.x,u0.y,u0.z,u0.w, u1.x,u1.y,u1.z,u1.w,
                    u2.x,u2.y,u2.z,u2.w, u3.x,u3.y,u3.z,u3.w};
    float ss[16] = {sv0.x,sv0.y,sv0.z,sv0.w, sv1.x,sv1.y,sv1.z,sv1.w,
                    sv2.x,sv2.y,sv2.z,sv2.w, sv3.x,sv3.y,sv3.z,sv3.w};
    float bs[16] = {bv0.x,bv0.y,bv0.z,bv0.w, bv1.x,bv1.y,bv1.z,bv1.w,
                    bv2.x,bv2.y,bv2.z,bv2.w, bv3.x,bv3.y,bv3.z,bv3.w};
    float sum = 0.f;
    #pragma unroll
    for (int i=0;i<16;++i) sum += xs[i];
    sum += __shfl_xor(sum, 16, 64);
    sum += __shfl_xor(sum, 32, 64);
    float mean = sum * (1.f/64.f);
    float sq = 0.f;
    #pragma unroll
    for (int i=0;i<16;++i) { float d = xs[i]-mean; sq += d*d; }
    sq += __shfl_xor(sq, 16, 64);
    sq += __shfl_xor(sq, 32, 64);
    float inv = rsqrtf(sq*(1.f/64.f) + 1e-6f);
    bf16x8 a0, a1;
    #pragma unroll
    for (int i=0;i<8;++i) a0[i] = f2bf((xs[i]  -mean)*inv*ss[i]   + bs[i]);
    #pragma unroll
    for (int i=0;i<8;++i) a1[i] = f2bf((xs[8+i]-mean)*inv*ss[8+i] + bs[8+i]);
    afr[0] = a0; afr[1] = a1;
  } else {
    const short* arow = (const short*)Ap + (size_t)row*K + kq*8;
    #pragma unroll
    for (int ks=0; ks<KSTEPS; ++ks) afr[ks] = *(const bf16x8*)(arow + ks*32);
  }

  #pragma unroll
  for (int ks=0; ks<KSTEPS; ++ks) {
    #pragma unroll
    for (int c=0; c<CT; ++c) {
      bf16x8 bfr = *(const bf16x8*)(WT + (size_t)(col0 + c*16 + r)*K + ks*32 + kq*8);
      acc[c] = __builtin_amdgcn_mfma_f32_16x16x32_bf16(afr[ks], bfr, acc[c], 0, 0, 0);
    }
  }

  const int orow0 = blockIdx.x*64 + wv*16 + kq*4;  // C/D: row=(lane>>4)*4+reg, col=lane&15
  #pragma unroll
  for (int c=0; c<CT; ++c) {
    int cc = col0 + c*16 + r;
    float bv = bias[cc];
    #pragma unroll
    for (int j=0;j<4;++j) {
      int rr = orow0 + j;
      float val = (acc[c][j] + bv) * scale;
      if constexpr (DOGELU) val = gelu_tanh(val);
      size_t oi = (size_t)rr*N + cc;
      if constexpr (OUTB) {
        ((__hip_bfloat16*)O)[oi] = __float2bfloat16(val);
      } else {
        float* Of = (float*)O;
        if constexpr (RES) val += Of[oi];
        Of[oi] = val;
      }
    }
  }
}

// ---------- sliding-window attention ----------
// grid (16, 32): 256 queries per block, 256 threads.
// thread t: qg = t>>2 owns queries 4qg..4qg+3; chunk c = t&3 covers rel = 4qg+c+4i.
// K/V staged f32 transposed [dim_pair][key]; maskless softmax (scores provably small),
// chunk partials combine exactly via shfl_xor. Output bf16.
__global__ __launch_bounds__(256) void attn_kernel(const float* __restrict__ q,
    const float* __restrict__ k, const float* __restrict__ v, __hip_bfloat16* __restrict__ out)
{
  const int qt = blockIdx.x, bh = blockIdx.y;
  const int b = bh >> 3, hh = bh & 7;
  const int t = threadIdx.x;
  const int q0 = qt << 8;
  const int kbase = q0 - 256;

  __shared__ float2 sK[4][768];
  __shared__ float2 sV[4][768];

  const float* kb_ = k + ((size_t)b*SB)*DM + hh*DH;
  const float* vb_ = v + ((size_t)b*SB)*DM + hh*DH;

  for (int e = t; e < 1536; e += 256) {
    int rel = e >> 1, dq = e & 1;
    int g = kbase + rel;
    float4 kv = make_float4(0.f,0.f,0.f,0.f), vv = make_float4(0.f,0.f,0.f,0.f);
    if ((unsigned)g < (unsigned)SB) {
      kv = *(const float4*)(kb_ + (size_t)g*DM + 4*dq);
      vv = *(const float4*)(vb_ + (size_t)g*DM + 4*dq);
    }
    sK[2*dq+0][rel] = make_float2(kv.x, kv.y);
    sK[2*dq+1][rel] = make_float2(kv.z, kv.w);
    sV[2*dq+0][rel] = make_float2(vv.x, vv.y);
    sV[2*dq+1][rel] = make_float2(vv.z, vv.w);
  }
  __syncthreads();

  const int qg = t >> 2;
  const int c  = t & 3;
  const int qa = q0 + 4*qg;

  float qf[4][8];
  #pragma unroll
  for (int j = 0; j < 4; ++j) {
    const float* qp = q + ((size_t)b*SB + qa + j)*DM + hh*DH;
    float4 x0 = *(const float4*)qp;
    float4 x1 = *(const float4*)(qp+4);
    qf[j][0]=x0.x; qf[j][1]=x0.y; qf[j][2]=x0.z; qf[j][3]=x0.w;
    qf[j][4]=x1.x; qf[j][5]=x1.y; qf[j][6]=x1.z; qf[j][7]=x1.w;
  }

  float o[4][8];
  float l[4] = {0.f,0.f,0.f,0.f};
  #pragma unroll
  for (int j=0;j<4;++j)
    #pragma unroll
    for (int d=0;d<8;++d) o[j][d]=0.f;

  int rel = 4*qg + c;
  for (int i = 0; i < 129; ++i, rel += 4) {
    float2 k0 = sK[0][rel], k1 = sK[1][rel], k2 = sK[2][rel], k3 = sK[3][rel];
    float2 v0 = sV[0][rel], v1 = sV[1][rel], v2 = sV[2][rel], v3 = sV[3][rel];
    float kf[8] = {k0.x,k0.y,k1.x,k1.y,k2.x,k2.y,k3.x,k3.y};
    float vf[8] = {v0.x,v0.y,v1.x,v1.y,v2.x,v2.y,v3.x,v3.y};
    int g = kbase + rel;
    bool gok = (unsigned)g < (unsigned)SB;
    int t0 = c + 4*i;
    #pragma unroll
    for (int j = 0; j < 4; ++j) {
      float s = 0.f;
      #pragma unroll
      for (int d = 0; d < 8; ++d) s = fmaf(qf[j][d], kf[d], s);
      bool ok = gok && ((unsigned)(t0 - j) <= 512u);
      float p = ok ? __expf(s) : 0.f;
      l[j] += p;
      #pragma unroll
      for (int d = 0; d < 8; ++d) o[j][d] = fmaf(p, vf[d], o[j][d]);
    }
  }

  #pragma unroll
  for (int j = 0; j < 4; ++j) {
    l[j] += __shfl_xor(l[j], 1, 64);
    l[j] += __shfl_xor(l[j], 2, 64);
    #pragma unroll
    for (int d = 0; d < 8; ++d) {
      o[j][d] += __shfl_xor(o[j][d], 1, 64);
      o[j][d] += __shfl_xor(o[j][d], 2, 64);
    }
  }
  if (c == 0) {
    #pragma unroll
    for (int j = 0; j < 4; ++j) {
      float rcp = 1.f / l[j];
      short tmp[8];
      #pragma unroll
      for (int d = 0; d < 8; ++d) tmp[d] = f2bf(o[j][d]*rcp);
      *(uint4*)(out + ((size_t)b*SB + qa + j)*DM + hh*DH) = *(uint4*)tmp;
    }
  }
}

// ---------- mean-pool partials + classifier ----------
__global__ __launch_bounds__(256) void pool_partial(const float* __restrict__ a, float* __restrict__ part)
{
  int b = blockIdx.x, sb = blockIdx.y;     // grid (4,16)
  int d = threadIdx.x & 63, seg = threadIdx.x >> 6;
  const float* base = a + ((size_t)(b*SB + sb*256 + seg*64))*DM + d;
  float sum = 0.f;
  #pragma unroll 4
  for (int i = 0; i < 64; ++i) sum += base[(size_t)i*DM];
  __shared__ float red[4][64];
  red[seg][d] = sum;
  __syncthreads();
  if (threadIdx.x < 64)
    part[(b*16 + sb)*64 + threadIdx.x] =
        red[0][threadIdx.x]+red[1][threadIdx.x]+red[2][threadIdx.x]+red[3][threadIdx.x];
}

__global__ __launch_bounds__(256) void pool_finalize(const float* __restrict__ part,
    const float* __restrict__ wcls, const float* __restrict__ bcls, float* __restrict__ out)
{
  int tid = threadIdx.x;
  int b = tid >> 6, d = tid & 63;
  float sum = 0.f;
  #pragma unroll
  for (int sb = 0; sb < 16; ++sb) sum += part[(b*16+sb)*64 + d];
  __shared__ float pooled[4][64];
  pooled[b][d] = sum * (1.f/4096.f);
  __syncthreads();
  if (tid < 40) {
    int bb = tid / 10, c = tid % 10;
    float acc = bcls[c];
    #pragma unroll
    for (int dd = 0; dd < 64; ++dd) acc = fmaf(pooled[bb][dd], wcls[dd*10 + c], acc);
    out[tid] = acc;
  }
}

// ---------- launcher ----------
extern "C" void kernel_launch(void* const* d_in, const int* in_sizes, int n_in,
                              void* d_out, int out_size, void* d_ws, size_t ws_size,
                              hipStream_t stream)
{
  const int*   x    = (const int*)d_in[0];
  const float* emb  = (const float*)d_in[1];
  const float* wq   = (const float*)d_in[2];
  const float* bq   = (const float*)d_in[3];
  const float* wk   = (const float*)d_in[4];
  const float* bk   = (const float*)d_in[5];
  const float* wv   = (const float*)d_in[6];
  const float* bv   = (const float*)d_in[7];
  const float* wo   = (const float*)d_in[8];
  const float* bo   = (const float*)d_in[9];
  const float* ln1s = (const float*)d_in[10];
  const float* ln1b = (const float*)d_in[11];
  const float* ln2s = (const float*)d_in[12];
  const float* ln2b = (const float*)d_in[13];
  const float* w1   = (const float*)d_in[14];
  const float* b1   = (const float*)d_in[15];
  const float* w2   = (const float*)d_in[16];
  const float* b2   = (const float*)d_in[17];
  const float* lnfs = (const float*)d_in[18];
  const float* lnfb = (const float*)d_in[19];
  const float* wcls = (const float*)d_in[20];
  const float* bcls = (const float*)d_in[21];
  float* out = (float*)d_out;

  char* wsb = (char*)d_ws;
  const size_t MB = 1u << 20;
  float* h  = (float*)(wsb);              // 4 MB f32 [16384][64]
  float* qf = (float*)(wsb + 4*MB);       // 4 MB
  float* kf = (float*)(wsb + 8*MB);       // 4 MB
  float* vf = (float*)(wsb + 12*MB);      // 4 MB
  __hip_bfloat16* ab  = (__hip_bfloat16*)(wsb + 16*MB);  // 2 MB bf16 [16384][64]
  __hip_bfloat16* mid = (__hip_bfloat16*)(wsb + 18*MB);  // 16 MB bf16 [16384][512]
  short* wqT = (short*)(wsb + 34*MB);               // 32 KB  (4 layers x [64][64])
  short* wkT = (short*)(wsb + 34*MB + 32*1024);
  short* wvT = (short*)(wsb + 34*MB + 64*1024);
  short* woT = (short*)(wsb + 34*MB + 96*1024);
  short* w1T = (short*)(wsb + 34*MB + 128*1024);    // 256 KB (4 x [512][64])
  short* w2T = (short*)(wsb + 34*MB + 384*1024);    // 256 KB (4 x [64][512]^T)
  float* part = (float*)(wsb + 35*MB);              // 16 KB

  wconv<<<dim3(80,4),256,0,stream>>>(wq,wk,wv,wo,w1,w2, wqT,wkT,wvT,woT,w1T,w2T);
  embed_kernel<<<4096,256,0,stream>>>(x, emb, h);
  const float qscale = 0.35355339059327373f;  // 1/sqrt(8)

  for (int l = 0; l < 4; ++l) {
    // qkv (LN1 fused): q,k,v f32
    gemm_mfma<2,2,true,false,false,false><<<dim3(256,2,3),256,0,stream>>>(
        h, ln1s+64*l, ln1b+64*l,
        wqT+4096*l, wkT+4096*l, wvT+4096*l,
        bq+64*l, bk+64*l, bv+64*l,
        qf, kf, vf, 64, qscale, 1.f, 1.f);
    attn_kernel<<<dim3(16,32),256,0,stream>>>(qf, kf, vf, ab);
    // attn out proj, residual into h
    gemm_mfma<2,2,false,false,false,true><<<dim3(256,2,1),256,0,stream>>>(
        ab, nullptr, nullptr,
        woT+4096*l, woT+4096*l, woT+4096*l,
        bo+64*l, bo+64*l, bo+64*l,
        h, h, h, 64, 1.f, 1.f, 1.f);
    // fc1 (LN2 fused) + GELU -> mid bf16
    gemm_mfma<4,2,true,true,true,false><<<dim3(256,8,1),256,0,stream>>>(
        h, ln2s+64*l, ln2b+64*l,
        w1T+32768*l, w1T+32768*l, w1T+32768*l,
        b1+512*l, b1+512*l, b1+512*l,
        mid, mid, mid, 512, 1.f, 1.f, 1.f);
    // fc2, residual into h
    gemm_mfma<2,16,false,false,false,true><<<dim3(256,2,1),256,0,stream>>>(
        mid, nullptr, nullptr,
        w2T+32768*l, w2T+32768*l, w2T+32768*l,
        b2+64*l, b2+64*l, b2+64*l,
        h, h, h, 64, 1.f, 1.f, 1.f);
  }
  ln_kernel<<<4096,256,0,stream>>>(h, lnfs, lnfb, qf);
  pool_partial<<<dim3(4,16),256,0,stream>>>(qf, part);
  pool_finalize<<<1,256,0,stream>>>(part, wcls, bcls, out);
}

// Round 5
// 317.458 us; speedup vs baseline: 2.7720x; 1.2400x over previous
//
#include <hip/hip_runtime.h>
#include <hip/hip_bf16.h>

#define DEV __device__ __forceinline__

typedef __attribute__((ext_vector_type(8))) short bf16x8;
typedef __attribute__((ext_vector_type(4))) float f32x4;
typedef __attribute__((ext_vector_type(16))) float f32x16;

// ---------- helpers ----------
DEV short f2bf(float x){ __hip_bfloat16 h = __float2bfloat16(x); return *(short*)&h; }
DEV unsigned pack2bf(float a, float b){
  return (unsigned)(unsigned short)f2bf(a) | ((unsigned)(unsigned short)f2bf(b) << 16);
}

DEV float gelu_tanh(float x){
  float x3 = x*x*x;
  float t = tanhf(0.7978845608028654f*(x + 0.044715f*x3));
  return 0.5f*x*(1.f + t);
}

// dims
#define SB 4096
#define NT 16384   // B*S
#define DM 64
#define NH 8
#define DH 8

// ---------- embedding + sinusoid pos emb ----------
__global__ __launch_bounds__(256) void embed_kernel(const int* __restrict__ x,
    const float* __restrict__ emb, float* __restrict__ h)
{
  int i = blockIdx.x*256 + threadIdx.x;        // 0 .. NT*64
  int t = i >> 6, d = i & 63;
  int s = t & (SB-1);
  int tok = x[t];
  float fe = (float)(d & ~1) * (1.0f/64.0f);
  float inv = expf(-9.210340371976184f * fe);  // 10000^{-fe}
  float ang = (float)s * inv;
  float pe = (d & 1) ? cosf(ang) : sinf(ang);
  h[i] = emb[tok*DM + d] + pe;
}

// ---------- layernorm (final only): one wave per 64-wide row ----------
__global__ __launch_bounds__(256) void ln_kernel(const float* __restrict__ x,
    const float* __restrict__ s, const float* __restrict__ b, float* __restrict__ o)
{
  int lane = threadIdx.x & 63;
  int row = blockIdx.x*4 + (threadIdx.x >> 6);
  float v = x[(size_t)row*DM + lane];
  float sum = v;
  #pragma unroll
  for (int m=1; m<64; m<<=1) sum += __shfl_xor(sum, m, 64);
  float mean = sum * (1.f/64.f);
  float c = v - mean;
  float sq = c*c;
  #pragma unroll
  for (int m=1; m<64; m<<=1) sq += __shfl_xor(sq, m, 64);
  float inv = rsqrtf(sq*(1.f/64.f) + 1e-6f);
  o[(size_t)row*DM + lane] = c*inv*s[lane] + b[lane];
}

// ---------- weight convert+transpose: f32 [K][N] -> bf16 [N][K], 32x32 tiles ----------
__global__ __launch_bounds__(256) void wconv(
    const float* __restrict__ wq, const float* __restrict__ wk,
    const float* __restrict__ wv, const float* __restrict__ wo,
    const float* __restrict__ w1, const float* __restrict__ w2,
    short* __restrict__ wqT, short* __restrict__ wkT,
    short* __restrict__ wvT, short* __restrict__ woT,
    short* __restrict__ w1T, short* __restrict__ w2T)
{
  int t = blockIdx.x, l = blockIdx.y;
  const float* src; short* dst; int K, N, kt, nt;
  if (t < 16) {
    int m = t >> 2, sub = t & 3; kt = sub >> 1; nt = sub & 1; K = 64; N = 64;
    const float* s4[4] = {wq, wk, wv, wo};
    short*       d4[4] = {wqT, wkT, wvT, woT};
    src = s4[m] + l*4096; dst = d4[m] + l*4096;
  } else if (t < 48) {
    kt = (t-16) >> 4; nt = (t-16) & 15; K = 64; N = 512;
    src = w1 + l*32768; dst = w1T + l*32768;
  } else {
    kt = (t-48) >> 1; nt = (t-48) & 1; K = 512; N = 64;   // FIX: &1 (round-4 typo was &15)
    src = w2 + l*32768; dst = w2T + l*32768;
  }
  __shared__ float lds[32][33];
  int tx = threadIdx.x & 31, ty = threadIdx.x >> 5;
  int k0 = kt*32, n0 = nt*32;
  #pragma unroll
  for (int j=0;j<4;++j) lds[ty+8*j][tx] = src[(size_t)(k0+ty+8*j)*N + n0 + tx];
  __syncthreads();
  #pragma unroll
  for (int j=0;j<4;++j) {
    int nn = ty+8*j;
    dst[(size_t)(n0+nn)*K + k0 + tx] = f2bf(lds[tx][nn]);
  }
}

// ---------- MFMA GEMM: O = act((A @ W + bias)*scale) [+O] ----------
template<int CT, int KSTEPS, bool LNF, bool OUTB, bool DOGELU, bool RES>
__global__ __launch_bounds__(256) void gemm_mfma(
    const void* __restrict__ Ap,
    const float* __restrict__ lns, const float* __restrict__ lnb,
    const short* __restrict__ WT0, const short* __restrict__ WT1, const short* __restrict__ WT2,
    const float* __restrict__ B0, const float* __restrict__ B1, const float* __restrict__ B2,
    void* __restrict__ O0, void* __restrict__ O1, void* __restrict__ O2,
    int N, float s0_, float s1_, float s2_)
{
  constexpr int K = KSTEPS*32;
  static_assert(!LNF || KSTEPS == 2, "LN fusion requires K==64");
  const int z = blockIdx.z;
  const short* WT   = z==0?WT0:(z==1?WT1:WT2);
  const float* bias = z==0?B0:(z==1?B1:B2);
  void* O           = z==0?O0:(z==1?O1:O2);
  const float scale = z==0?s0_:(z==1?s1_:s2_);

  const int lane = threadIdx.x & 63;
  const int wv = threadIdx.x >> 6;
  const int r = lane & 15, kq = lane >> 4;
  const int row = blockIdx.x*64 + wv*16 + r;
  const int col0 = blockIdx.y * (CT*16);

  f32x4 acc[CT];
  #pragma unroll
  for (int c=0;c<CT;++c) acc[c] = (f32x4){0.f,0.f,0.f,0.f};

  bf16x8 afr[KSTEPS];
  if constexpr (LNF) {
    const float* hrow = (const float*)Ap + (size_t)row*64 + kq*8;
    float4 u0 = *(const float4*)(hrow);
    float4 u1 = *(const float4*)(hrow+4);
    float4 u2 = *(const float4*)(hrow+32);
    float4 u3 = *(const float4*)(hrow+36);
    const float* sp = lns + kq*8;
    float4 sv0 = *(const float4*)(sp), sv1 = *(const float4*)(sp+4);
    float4 sv2 = *(const float4*)(sp+32), sv3 = *(const float4*)(sp+36);
    const float* bp = lnb + kq*8;
    float4 bv0 = *(const float4*)(bp), bv1 = *(const float4*)(bp+4);
    float4 bv2 = *(const float4*)(bp+32), bv3 = *(const float4*)(bp+36);
    float xs[16] = {u0.x,u0.y,u0.z,u0.w, u1.x,u1.y,u1.z,u1.w,
                    u2.x,u2.y,u2.z,u2.w, u3.x,u3.y,u3.z,u3.w};
    float ss[16] = {sv0.x,sv0.y,sv0.z,sv0.w, sv1.x,sv1.y,sv1.z,sv1.w,
                    sv2.x,sv2.y,sv2.z,sv2.w, sv3.x,sv3.y,sv3.z,sv3.w};
    float bs[16] = {bv0.x,bv0.y,bv0.z,bv0.w, bv1.x,bv1.y,bv1.z,bv1.w,
                    bv2.x,bv2.y,bv2.z,bv2.w, bv3.x,bv3.y,bv3.z,bv3.w};
    float sum = 0.f;
    #pragma unroll
    for (int i=0;i<16;++i) sum += xs[i];
    sum += __shfl_xor(sum, 16, 64);
    sum += __shfl_xor(sum, 32, 64);
    float mean = sum * (1.f/64.f);
    float sq = 0.f;
    #pragma unroll
    for (int i=0;i<16;++i) { float d = xs[i]-mean; sq += d*d; }
    sq += __shfl_xor(sq, 16, 64);
    sq += __shfl_xor(sq, 32, 64);
    float inv = rsqrtf(sq*(1.f/64.f) + 1e-6f);
    bf16x8 a0, a1;
    #pragma unroll
    for (int i=0;i<8;++i) a0[i] = f2bf((xs[i]  -mean)*inv*ss[i]   + bs[i]);
    #pragma unroll
    for (int i=0;i<8;++i) a1[i] = f2bf((xs[8+i]-mean)*inv*ss[8+i] + bs[8+i]);
    afr[0] = a0; afr[1] = a1;
  } else {
    const short* arow = (const short*)Ap + (size_t)row*K + kq*8;
    #pragma unroll
    for (int ks=0; ks<KSTEPS; ++ks) afr[ks] = *(const bf16x8*)(arow + ks*32);
  }

  #pragma unroll
  for (int ks=0; ks<KSTEPS; ++ks) {
    #pragma unroll
    for (int c=0; c<CT; ++c) {
      bf16x8 bfr = *(const bf16x8*)(WT + (size_t)(col0 + c*16 + r)*K + ks*32 + kq*8);
      acc[c] = __builtin_amdgcn_mfma_f32_16x16x32_bf16(afr[ks], bfr, acc[c], 0, 0, 0);
    }
  }

  const int orow0 = blockIdx.x*64 + wv*16 + kq*4;
  #pragma unroll
  for (int c=0; c<CT; ++c) {
    int cc = col0 + c*16 + r;
    float bv = bias[cc];
    #pragma unroll
    for (int j=0;j<4;++j) {
      int rr = orow0 + j;
      float val = (acc[c][j] + bv) * scale;
      if constexpr (DOGELU) val = gelu_tanh(val);
      size_t oi = (size_t)rr*N + cc;
      if constexpr (OUTB) {
        ((__hip_bfloat16*)O)[oi] = __float2bfloat16(val);
      } else {
        float* Of = (float*)O;
        if constexpr (RES) val += Of[oi];
        Of[oi] = val;
      }
    }
  }
}

// ---------- sliding-window attention v3: MFMA ----------
// grid (32, 32): 128 queries/block, 4 waves, wave = 32 queries.
// Swapped scores: S^T = mfma_32x32x16(K, Q) -> lane holds (col=q, 16 key-rows).
// PV: O^T = mfma_32x32x16(V^T, P^T); P^T B-frag built in-register via shfl_xor(32).
// Maskless softmax (scores tiny); bulk tiles t=1..15 provably in-band.
#define VSTR 664
__global__ __launch_bounds__(256) void attn_kernel(
    const unsigned short* __restrict__ qg_,
    const unsigned short* __restrict__ kg_,
    const unsigned short* __restrict__ vg_,
    __hip_bfloat16* __restrict__ out)
{
  const int qblk = blockIdx.x, bh = blockIdx.y;
  const int b = bh >> 3, hh = bh & 7;
  const int tid = threadIdx.x;
  const int q0b = qblk << 7;          // 128 queries per block
  const int kbase = q0b - 256;        // window: 640 keys

  __shared__ unsigned short Ks[640*8];     // [key][8 dims]
  __shared__ unsigned short Vs[8*VSTR];    // [dim][key], stride 664 (conflict-free)

  const unsigned short* kgp = kg_ + ((size_t)b*SB)*DM + hh*DH;
  const unsigned short* vgp = vg_ + ((size_t)b*SB)*DM + hh*DH;

  for (int e = tid; e < 640; e += 256) {
    int g = kbase + e;
    uint4 kv = make_uint4(0,0,0,0), vv = make_uint4(0,0,0,0);
    if ((unsigned)g < (unsigned)SB) {
      kv = *(const uint4*)(kgp + (size_t)g*DM);
      vv = *(const uint4*)(vgp + (size_t)g*DM);
    }
    *(uint4*)(Ks + e*8) = kv;
    const unsigned short* pv = (const unsigned short*)&vv;
    #pragma unroll
    for (int d = 0; d < 8; ++d) Vs[d*VSTR + e] = pv[d];
  }
  __syncthreads();

  const int w = tid >> 6;
  const int lane = tid & 63;
  const int qc = lane & 31;           // column: query index (or dim for V A-frag)
  const int h  = lane >> 5;           // half
  const int q0w = q0b + 32*w;
  const int qglob = q0w + qc;

  // Q B-frag: lane(col=q, half h) holds Q[q][8h..8h+7]; dims 8..15 are zero.
  bf16x8 qfrag = {};
  if (h == 0) qfrag = *(const bf16x8*)(qg_ + ((size_t)b*SB + qglob)*DM + hh*DH);

  f32x16 oacc = {};
  float lacc = 0.f;

  for (int t = 0; t <= 16; ++t) {
    const int k0l = 32*w + 32*t;       // block-local key base
    const int k0g = kbase + k0l;       // global key base
    if (k0g > SB-1 || k0g + 31 < 0) continue;   // fully out of range

    // A-frag = K tile: lane(row=key, h) holds K[key][8h..8h+7] (h==1 -> zero dims)
    bf16x8 kfrag = {};
    if (h == 0) kfrag = *(const bf16x8*)(Ks + (k0l + qc)*8);

    f32x16 s = __builtin_amdgcn_mfma_f32_32x32x16_bf16(kfrag, qfrag, (f32x16){}, 0, 0, 0);

    // rows held by this lane: key_local = (r&3) + 8*(r>>2) + 4*h
    float p[16];
    bool needmask = (t == 0) | (t == 16) | (k0g < 0) | (k0g + 31 > SB-1);
    if (needmask) {
      #pragma unroll
      for (int r = 0; r < 16; ++r) {
        int klg = k0g + (r&3) + 8*(r>>2) + 4*h;
        bool ok = ((unsigned)(klg - qglob + 256) <= 512u) && ((unsigned)klg < (unsigned)SB);
        p[r] = ok ? __expf(s[r]) : 0.f;
      }
    } else {
      #pragma unroll
      for (int r = 0; r < 16; ++r) p[r] = __expf(s[r]);
    }
    #pragma unroll
    for (int r = 0; r < 16; ++r) lacc += p[r];

    // pack to bf16 pairs: pk[j] = keys {2j,2j+1} pattern within quads
    unsigned pk[8];
    #pragma unroll
    for (int j = 0; j < 8; ++j) pk[j] = pack2bf(p[2*j], p[2*j+1]);
    unsigned sw[8];
    #pragma unroll
    for (int j = 0; j < 8; ++j) sw[j] = __shfl_xor(pk[j], 32, 64);

    // PV mfma #1: keys k0l .. k0l+15
    union { unsigned u[4]; bf16x8 v; } b1;
    b1.u[0] = h ? sw[2] : pk[0];
    b1.u[1] = h ? sw[3] : pk[1];
    b1.u[2] = h ? pk[2] : sw[0];
    b1.u[3] = h ? pk[3] : sw[1];
    bf16x8 va1 = {};
    if (qc < 8) va1 = *(const bf16x8*)(Vs + qc*VSTR + k0l + 8*h);
    oacc = __builtin_amdgcn_mfma_f32_32x32x16_bf16(va1, b1.v, oacc, 0, 0, 0);

    // PV mfma #2: keys k0l+16 .. k0l+31
    union { unsigned u[4]; bf16x8 v; } b2;
    b2.u[0] = h ? sw[6] : pk[4];
    b2.u[1] = h ? sw[7] : pk[5];
    b2.u[2] = h ? pk[6] : sw[4];
    b2.u[3] = h ? pk[7] : sw[5];
    bf16x8 va2 = {};
    if (qc < 8) va2 = *(const bf16x8*)(Vs + qc*VSTR + k0l + 16 + 8*h);
    oacc = __builtin_amdgcn_mfma_f32_32x32x16_bf16(va2, b2.v, oacc, 0, 0, 0);
  }

  // denom: this lane holds half the keys for query qc; other half in lane^32
  float lsum = lacc + __shfl_xor(lacc, 32, 64);
  float rcp = 1.f / lsum;
  // O^T: lane(col=q, h) regs 0..3 = dims 4h+0..3
  unsigned short ov[4];
  #pragma unroll
  for (int j = 0; j < 4; ++j) ov[j] = (unsigned short)f2bf(oacc[j] * rcp);
  *(uint2*)(out + ((size_t)b*SB + qglob)*DM + hh*DH + 4*h) = *(uint2*)ov;
}

// ---------- mean-pool partials + classifier ----------
__global__ __launch_bounds__(256) void pool_partial(const float* __restrict__ a, float* __restrict__ part)
{
  int b = blockIdx.x, sb = blockIdx.y;     // grid (4,16)
  int d = threadIdx.x & 63, seg = threadIdx.x >> 6;
  const float* base = a + ((size_t)(b*SB + sb*256 + seg*64))*DM + d;
  float sum = 0.f;
  #pragma unroll 4
  for (int i = 0; i < 64; ++i) sum += base[(size_t)i*DM];
  __shared__ float red[4][64];
  red[seg][d] = sum;
  __syncthreads();
  if (threadIdx.x < 64)
    part[(b*16 + sb)*64 + threadIdx.x] =
        red[0][threadIdx.x]+red[1][threadIdx.x]+red[2][threadIdx.x]+red[3][threadIdx.x];
}

__global__ __launch_bounds__(256) void pool_finalize(const float* __restrict__ part,
    const float* __restrict__ wcls, const float* __restrict__ bcls, float* __restrict__ out)
{
  int tid = threadIdx.x;
  int b = tid >> 6, d = tid & 63;
  float sum = 0.f;
  #pragma unroll
  for (int sb = 0; sb < 16; ++sb) sum += part[(b*16+sb)*64 + d];
  __shared__ float pooled[4][64];
  pooled[b][d] = sum * (1.f/4096.f);
  __syncthreads();
  if (tid < 40) {
    int bb = tid / 10, c = tid % 10;
    float acc = bcls[c];
    #pragma unroll
    for (int dd = 0; dd < 64; ++dd) acc = fmaf(pooled[bb][dd], wcls[dd*10 + c], acc);
    out[tid] = acc;
  }
}

// ---------- launcher ----------
extern "C" void kernel_launch(void* const* d_in, const int* in_sizes, int n_in,
                              void* d_out, int out_size, void* d_ws, size_t ws_size,
                              hipStream_t stream)
{
  const int*   x    = (const int*)d_in[0];
  const float* emb  = (const float*)d_in[1];
  const float* wq   = (const float*)d_in[2];
  const float* bq   = (const float*)d_in[3];
  const float* wk   = (const float*)d_in[4];
  const float* bk   = (const float*)d_in[5];
  const float* wv   = (const float*)d_in[6];
  const float* bv   = (const float*)d_in[7];
  const float* wo   = (const float*)d_in[8];
  const float* bo   = (const float*)d_in[9];
  const float* ln1s = (const float*)d_in[10];
  const float* ln1b = (const float*)d_in[11];
  const float* ln2s = (const float*)d_in[12];
  const float* ln2b = (const float*)d_in[13];
  const float* w1   = (const float*)d_in[14];
  const float* b1   = (const float*)d_in[15];
  const float* w2   = (const float*)d_in[16];
  const float* b2   = (const float*)d_in[17];
  const float* lnfs = (const float*)d_in[18];
  const float* lnfb = (const float*)d_in[19];
  const float* wcls = (const float*)d_in[20];
  const float* bcls = (const float*)d_in[21];
  float* out = (float*)d_out;

  char* wsb = (char*)d_ws;
  const size_t MB = 1u << 20;
  float* h  = (float*)(wsb);                             // 4 MB f32 [16384][64]
  unsigned short* qb2 = (unsigned short*)(wsb + 4*MB);   // 2 MB bf16 [16384][64]
  unsigned short* kb2 = (unsigned short*)(wsb + 6*MB);   // 2 MB
  unsigned short* vb2 = (unsigned short*)(wsb + 8*MB);   // 2 MB
  __hip_bfloat16* ab  = (__hip_bfloat16*)(wsb + 10*MB);  // 2 MB bf16 [16384][64]
  __hip_bfloat16* mid = (__hip_bfloat16*)(wsb + 12*MB);  // 16 MB bf16 [16384][512]
  float* fscr = (float*)(wsb + 28*MB);                   // 4 MB f32 scratch (final LN)
  short* wqT = (short*)(wsb + 33*MB);                    // transposed weights
  short* wkT = (short*)(wsb + 33*MB + 32*1024);
  short* wvT = (short*)(wsb + 33*MB + 64*1024);
  short* woT = (short*)(wsb + 33*MB + 96*1024);
  short* w1T = (short*)(wsb + 33*MB + 128*1024);
  short* w2T = (short*)(wsb + 33*MB + 384*1024);
  float* part = (float*)(wsb + 34*MB);

  wconv<<<dim3(80,4),256,0,stream>>>(wq,wk,wv,wo,w1,w2, wqT,wkT,wvT,woT,w1T,w2T);
  embed_kernel<<<4096,256,0,stream>>>(x, emb, h);
  const float qscale = 0.35355339059327373f;  // 1/sqrt(8)

  for (int l = 0; l < 4; ++l) {
    // qkv (LN1 fused) -> bf16 q,k,v
    gemm_mfma<2,2,true,true,false,false><<<dim3(256,2,3),256,0,stream>>>(
        h, ln1s+64*l, ln1b+64*l,
        wqT+4096*l, wkT+4096*l, wvT+4096*l,
        bq+64*l, bk+64*l, bv+64*l,
        qb2, kb2, vb2, 64, qscale, 1.f, 1.f);
    attn_kernel<<<dim3(32,32),256,0,stream>>>(qb2, kb2, vb2, ab);
    // attn out proj, residual into h
    gemm_mfma<2,2,false,false,false,true><<<dim3(256,2,1),256,0,stream>>>(
        ab, nullptr, nullptr,
        woT+4096*l, woT+4096*l, woT+4096*l,
        bo+64*l, bo+64*l, bo+64*l,
        h, h, h, 64, 1.f, 1.f, 1.f);
    // fc1 (LN2 fused) + GELU -> mid bf16
    gemm_mfma<4,2,true,true,true,false><<<dim3(256,8,1),256,0,stream>>>(
        h, ln2s+64*l, ln2b+64*l,
        w1T+32768*l, w1T+32768*l, w1T+32768*l,
        b1+512*l, b1+512*l, b1+512*l,
        mid, mid, mid, 512, 1.f, 1.f, 1.f);
    // fc2, residual into h
    gemm_mfma<2,16,false,false,false,true><<<dim3(256,2,1),256,0,stream>>>(
        mid, nullptr, nullptr,
        w2T+32768*l, w2T+32768*l, w2T+32768*l,
        b2+64*l, b2+64*l, b2+64*l,
        h, h, h, 64, 1.f, 1.f, 1.f);
  }
  ln_kernel<<<4096,256,0,stream>>>(h, lnfs, lnfb, fscr);
  pool_partial<<<dim3(4,16),256,0,stream>>>(fscr, part);
  pool_finalize<<<1,256,0,stream>>>(part, wcls, bcls, out);
}

// Round 6
// 251.726 us; speedup vs baseline: 3.4958x; 1.2611x over previous
//
#include <hip/hip_runtime.h>
#include <hip/hip_bf16.h>

#define DEV __device__ __forceinline__

typedef __attribute__((ext_vector_type(8))) short bf16x8;
typedef __attribute__((ext_vector_type(4))) float f32x4;
typedef __attribute__((ext_vector_type(16))) float f32x16;

// ---------- helpers ----------
DEV short f2bf(float x){ __hip_bfloat16 h = __float2bfloat16(x); return *(short*)&h; }
DEV unsigned pack2bf(float a, float b){
  return (unsigned)(unsigned short)f2bf(a) | ((unsigned)(unsigned short)f2bf(b) << 16);
}

DEV float gelu_tanh(float x){
  float x3 = x*x*x;
  float t = tanhf(0.7978845608028654f*(x + 0.044715f*x3));
  return 0.5f*x*(1.f + t);
}

// dims
#define SB 4096
#define NT 16384   // B*S
#define DM 64

// ---------- weight convert+transpose: f32 [K][N] -> bf16 [N][K], 32x32 tiles ----------
__global__ __launch_bounds__(256) void wconv(
    const float* __restrict__ wq, const float* __restrict__ wk,
    const float* __restrict__ wv, const float* __restrict__ wo,
    const float* __restrict__ w1, const float* __restrict__ w2,
    short* __restrict__ wqT, short* __restrict__ wkT,
    short* __restrict__ wvT, short* __restrict__ woT,
    short* __restrict__ w1T, short* __restrict__ w2T)
{
  int t = blockIdx.x, l = blockIdx.y;
  const float* src; short* dst; int K, N, kt, nt;
  if (t < 16) {
    int m = t >> 2, sub = t & 3; kt = sub >> 1; nt = sub & 1; K = 64; N = 64;
    const float* s4[4] = {wq, wk, wv, wo};
    short*       d4[4] = {wqT, wkT, wvT, woT};
    src = s4[m] + l*4096; dst = d4[m] + l*4096;
  } else if (t < 48) {
    kt = (t-16) >> 4; nt = (t-16) & 15; K = 64; N = 512;
    src = w1 + l*32768; dst = w1T + l*32768;
  } else {
    kt = (t-48) >> 1; nt = (t-48) & 1; K = 512; N = 64;
    src = w2 + l*32768; dst = w2T + l*32768;
  }
  __shared__ float lds[32][33];
  int tx = threadIdx.x & 31, ty = threadIdx.x >> 5;
  int k0 = kt*32, n0 = nt*32;
  #pragma unroll
  for (int j=0;j<4;++j) lds[ty+8*j][tx] = src[(size_t)(k0+ty+8*j)*N + n0 + tx];
  __syncthreads();
  #pragma unroll
  for (int j=0;j<4;++j) {
    int nn = ty+8*j;
    dst[(size_t)(n0+nn)*K + k0 + tx] = f2bf(lds[tx][nn]);
  }
}

// ---------- fused building blocks ----------
// A-frag builders: read f32 row from LDS, optional LN, convert to bf16 frags (K=64).
DEV void make_frags(const float* rowp, int kq, bf16x8& a0, bf16x8& a1){
  #pragma unroll
  for (int i=0;i<8;++i) a0[i] = f2bf(rowp[kq*8+i]);
  #pragma unroll
  for (int i=0;i<8;++i) a1[i] = f2bf(rowp[32+kq*8+i]);
}
DEV void make_frags_ln(const float* rowp, float mean, float inv,
    const float* __restrict__ s, const float* __restrict__ b, int kq,
    bf16x8& a0, bf16x8& a1){
  #pragma unroll
  for (int i=0;i<8;++i) a0[i] = f2bf((rowp[kq*8+i]-mean)*inv*s[kq*8+i]+b[kq*8+i]);
  #pragma unroll
  for (int i=0;i<8;++i) a1[i] = f2bf((rowp[32+kq*8+i]-mean)*inv*s[32+kq*8+i]+b[32+kq*8+i]);
}
// wave GEMM: 16 rows x 32 cols, K=64, B from bf16 [N][KS] transposed weights.
template<int KS>
DEV void gemm2(const bf16x8& a0, const bf16x8& a1, const short* __restrict__ WT,
               int cc0, int kq, int r, f32x4* acc){
  #pragma unroll
  for (int ct=0; ct<2; ++ct){
    const short* wp = WT + (size_t)(cc0 + ct*16 + r)*KS + kq*8;
    bf16x8 b0 = *(const bf16x8*)(wp);
    bf16x8 b1v = *(const bf16x8*)(wp + 32);
    acc[ct] = __builtin_amdgcn_mfma_f32_16x16x32_bf16(a0, b0,  acc[ct], 0, 0, 0);
    acc[ct] = __builtin_amdgcn_mfma_f32_16x16x32_bf16(a1, b1v, acc[ct], 0, 0, 0);
  }
}

// ---------- fused layer kernel ----------
// 32 rows/block, grid 512, 4 waves; wave w: rows 16*(w>>1).., cols 32*(w&1)..
// EMBED: embed+posemb -> h, LN1, qkv.
// else:  attnout+res -> LN2 -> 8x(fc1+gelu -> fc2 partial) -> +b2+res -> h,
//        then (!LAST: LN1+qkv of next layer | LAST: LNf + pool partial).
template<bool EMBED, bool LAST>
__global__ __launch_bounds__(256,2) void fused_kernel(
    const int* __restrict__ x, const float* __restrict__ emb,
    const unsigned short* __restrict__ ab,
    const short* __restrict__ woT, const float* __restrict__ bo,
    const float* __restrict__ ln2s, const float* __restrict__ ln2b,
    const short* __restrict__ w1T, const float* __restrict__ b1,
    const short* __restrict__ w2T, const float* __restrict__ b2,
    const float* __restrict__ lns, const float* __restrict__ lnb,   // LN1(next) or LNf
    const short* __restrict__ wqT, const short* __restrict__ wkT, const short* __restrict__ wvT,
    const float* __restrict__ bq, const float* __restrict__ bk, const float* __restrict__ bv,
    unsigned short* __restrict__ qo, unsigned short* __restrict__ ko, unsigned short* __restrict__ vo,
    float* __restrict__ h, float* __restrict__ part)
{
  __shared__ float hN[32][76];
  __shared__ float sc0[32][76];
  __shared__ float sc1[32][76];
  __shared__ float mu[32], iv[32];

  const int bid = blockIdx.x;
  const int row_g0 = bid * 32;
  const int tid = threadIdx.x;
  const int w = tid >> 6, lane = tid & 63;
  const int r = lane & 15, kq = lane >> 4;
  const int wr0 = (w >> 1) * 16;
  const int cc0 = (w & 1) * 32;
  const int srow = tid >> 3, sdq = tid & 7;   // stats/embed mapping: 8 threads/row

  if constexpr (EMBED) {
    int tg = row_g0 + srow;
    int s = tg & (SB-1);
    int tok = x[tg];
    #pragma unroll
    for (int i=0;i<8;++i) {
      int d = sdq*8 + i;
      float fe = (float)(d & ~1) * (1.0f/64.0f);
      float invk = __expf(-9.210340371976184f * fe);
      float ang = (float)s * invk;
      float pe = (d & 1) ? __cosf(ang) : __sinf(ang);
      float val = emb[tok*DM + d] + pe;
      hN[srow][d] = val;
      h[(size_t)tg*DM + d] = val;
    }
  } else {
    // attn-out projection + residual
    const short* abp = (const short*)(ab + (size_t)(row_g0 + wr0 + r)*DM + kq*8);
    bf16x8 a0 = *(const bf16x8*)abp;
    bf16x8 a1 = *(const bf16x8*)(abp + 32);
    f32x4 acc[2] = {(f32x4){0,0,0,0},(f32x4){0,0,0,0}};
    gemm2<64>(a0, a1, woT, cc0, kq, r, acc);
    #pragma unroll
    for (int ct=0; ct<2; ++ct) {
      int col = cc0 + ct*16 + r;
      #pragma unroll
      for (int j=0;j<4;++j) {
        int rl = wr0 + kq*4 + j;
        hN[rl][col] = acc[ct][j] + bo[col] + h[(size_t)(row_g0+rl)*DM + col];
      }
    }
  }
  __syncthreads();

  // LN stats (LN1 for EMBED, LN2 otherwise)
  {
    const float* p = &hN[srow][sdq*8];
    float v[8];
    #pragma unroll
    for (int i=0;i<8;++i) v[i] = p[i];
    float sum = 0.f;
    #pragma unroll
    for (int i=0;i<8;++i) sum += v[i];
    sum += __shfl_xor(sum, 1, 64); sum += __shfl_xor(sum, 2, 64); sum += __shfl_xor(sum, 4, 64);
    float mean = sum * (1.f/64.f);
    float sq = 0.f;
    #pragma unroll
    for (int i=0;i<8;++i) { float d = v[i]-mean; sq += d*d; }
    sq += __shfl_xor(sq, 1, 64); sq += __shfl_xor(sq, 2, 64); sq += __shfl_xor(sq, 4, 64);
    if (sdq == 0) { mu[srow] = mean; iv[srow] = rsqrtf(sq*(1.f/64.f) + 1e-6f); }
  }
  __syncthreads();

  if constexpr (!EMBED) {
    // FFN: A-frags (LN2 applied) are chunk-invariant
    bf16x8 a0, a1;
    make_frags_ln(&hN[wr0+r][0], mu[wr0+r], iv[wr0+r], ln2s, ln2b, kq, a0, a1);
    f32x4 acc2[2] = {(f32x4){0,0,0,0},(f32x4){0,0,0,0}};
    #pragma unroll
    for (int c=0; c<8; ++c) {
      float (*scp)[76] = (c & 1) ? sc1 : sc0;
      // fc1 chunk + gelu -> sc
      f32x4 acc1[2] = {(f32x4){0,0,0,0},(f32x4){0,0,0,0}};
      gemm2<64>(a0, a1, w1T + (size_t)c*64*64, cc0, kq, r, acc1);
      #pragma unroll
      for (int ct=0; ct<2; ++ct) {
        int col = cc0 + ct*16 + r;
        float bb = b1[c*64 + col];
        #pragma unroll
        for (int j=0;j<4;++j)
          scp[wr0 + kq*4 + j][col] = gelu_tanh(acc1[ct][j] + bb);
      }
      __syncthreads();
      // fc2 partial from sc
      bf16x8 m0, m1;
      make_frags(&scp[wr0+r][0], kq, m0, m1);
      gemm2<512>(m0, m1, w2T + c*64, cc0, kq, r, acc2);
    }
    // h_final = acc2 + b2 + residual(hN); update LDS + global
    #pragma unroll
    for (int ct=0; ct<2; ++ct) {
      int col = cc0 + ct*16 + r;
      float bb = b2[col];
      #pragma unroll
      for (int j=0;j<4;++j) {
        int rl = wr0 + kq*4 + j;
        float val = acc2[ct][j] + bb + hN[rl][col];
        hN[rl][col] = val;
        h[(size_t)(row_g0+rl)*DM + col] = val;
      }
    }
    __syncthreads();
    // LN stats for LN1(next) / LNf
    {
      const float* p = &hN[srow][sdq*8];
      float v[8];
      #pragma unroll
      for (int i=0;i<8;++i) v[i] = p[i];
      float sum = 0.f;
      #pragma unroll
      for (int i=0;i<8;++i) sum += v[i];
      sum += __shfl_xor(sum, 1, 64); sum += __shfl_xor(sum, 2, 64); sum += __shfl_xor(sum, 4, 64);
      float mean = sum * (1.f/64.f);
      float sq = 0.f;
      #pragma unroll
      for (int i=0;i<8;++i) { float d = v[i]-mean; sq += d*d; }
      sq += __shfl_xor(sq, 1, 64); sq += __shfl_xor(sq, 2, 64); sq += __shfl_xor(sq, 4, 64);
      if (sdq == 0) { mu[srow] = mean; iv[srow] = rsqrtf(sq*(1.f/64.f) + 1e-6f); }
    }
    __syncthreads();
  }

  if constexpr (!LAST) {
    // qkv of (next) layer
    const float qscale = 0.35355339059327373f;  // 1/sqrt(8)
    bf16x8 a0, a1;
    make_frags_ln(&hN[wr0+r][0], mu[wr0+r], iv[wr0+r], lns, lnb, kq, a0, a1);
    f32x4 aq[2] = {(f32x4){0,0,0,0},(f32x4){0,0,0,0}};
    f32x4 akk[2] = {(f32x4){0,0,0,0},(f32x4){0,0,0,0}};
    f32x4 av[2] = {(f32x4){0,0,0,0},(f32x4){0,0,0,0}};
    gemm2<64>(a0, a1, wqT, cc0, kq, r, aq);
    gemm2<64>(a0, a1, wkT, cc0, kq, r, akk);
    gemm2<64>(a0, a1, wvT, cc0, kq, r, av);
    #pragma unroll
    for (int ct=0; ct<2; ++ct) {
      int col = cc0 + ct*16 + r;
      float bqv = bq[col], bkv = bk[col], bvv = bv[col];
      #pragma unroll
      for (int j=0;j<4;++j) {
        size_t oi = (size_t)(row_g0 + wr0 + kq*4 + j)*DM + col;
        qo[oi] = (unsigned short)f2bf((aq[ct][j] + bqv)*qscale);
        ko[oi] = (unsigned short)f2bf(akk[ct][j] + bkv);
        vo[oi] = (unsigned short)f2bf(av[ct][j] + bvv);
      }
    }
  } else {
    // final LN + pool partial (sum of 32 rows per dim)
    float mean = mu[srow], inv = iv[srow];
    #pragma unroll
    for (int i=0;i<8;++i) {
      int d = sdq*8 + i;
      sc0[srow][d] = (hN[srow][d]-mean)*inv*lns[d] + lnb[d];
    }
    __syncthreads();
    if (tid < 64) {
      float s = 0.f;
      #pragma unroll 4
      for (int rr=0; rr<32; ++rr) s += sc0[rr][tid];
      part[bid*64 + tid] = s;
    }
  }
}

// ---------- sliding-window attention (MFMA, unchanged from round 5) ----------
#define VSTR 664
__global__ __launch_bounds__(256) void attn_kernel(
    const unsigned short* __restrict__ qg_,
    const unsigned short* __restrict__ kg_,
    const unsigned short* __restrict__ vg_,
    __hip_bfloat16* __restrict__ out)
{
  const int qblk = blockIdx.x, bh = blockIdx.y;
  const int b = bh >> 3, hh = bh & 7;
  const int tid = threadIdx.x;
  const int q0b = qblk << 7;
  const int kbase = q0b - 256;

  __shared__ unsigned short Ks[640*8];
  __shared__ unsigned short Vs[8*VSTR];

  const unsigned short* kgp = kg_ + ((size_t)b*SB)*DM + hh*8;
  const unsigned short* vgp = vg_ + ((size_t)b*SB)*DM + hh*8;

  for (int e = tid; e < 640; e += 256) {
    int g = kbase + e;
    uint4 kv = make_uint4(0,0,0,0), vv = make_uint4(0,0,0,0);
    if ((unsigned)g < (unsigned)SB) {
      kv = *(const uint4*)(kgp + (size_t)g*DM);
      vv = *(const uint4*)(vgp + (size_t)g*DM);
    }
    *(uint4*)(Ks + e*8) = kv;
    const unsigned short* pv = (const unsigned short*)&vv;
    #pragma unroll
    for (int d = 0; d < 8; ++d) Vs[d*VSTR + e] = pv[d];
  }
  __syncthreads();

  const int w = tid >> 6;
  const int lane = tid & 63;
  const int qc = lane & 31;
  const int hf = lane >> 5;
  const int qglob = q0b + 32*w + qc;

  bf16x8 qfrag = {};
  if (hf == 0) qfrag = *(const bf16x8*)(qg_ + ((size_t)b*SB + qglob)*DM + hh*8);

  f32x16 oacc = {};
  float lacc = 0.f;

  for (int t = 0; t <= 16; ++t) {
    const int k0l = 32*w + 32*t;
    const int k0g = kbase + k0l;
    if (k0g > SB-1 || k0g + 31 < 0) continue;

    bf16x8 kfrag = {};
    if (hf == 0) kfrag = *(const bf16x8*)(Ks + (k0l + qc)*8);

    f32x16 s = __builtin_amdgcn_mfma_f32_32x32x16_bf16(kfrag, qfrag, (f32x16){}, 0, 0, 0);

    float p[16];
    bool needmask = (t == 0) | (t == 16) | (k0g < 0) | (k0g + 31 > SB-1);
    if (needmask) {
      #pragma unroll
      for (int rr = 0; rr < 16; ++rr) {
        int klg = k0g + (rr&3) + 8*(rr>>2) + 4*hf;
        bool ok = ((unsigned)(klg - qglob + 256) <= 512u) && ((unsigned)klg < (unsigned)SB);
        p[rr] = ok ? __expf(s[rr]) : 0.f;
      }
    } else {
      #pragma unroll
      for (int rr = 0; rr < 16; ++rr) p[rr] = __expf(s[rr]);
    }
    #pragma unroll
    for (int rr = 0; rr < 16; ++rr) lacc += p[rr];

    unsigned pk[8];
    #pragma unroll
    for (int j = 0; j < 8; ++j) pk[j] = pack2bf(p[2*j], p[2*j+1]);
    unsigned sw[8];
    #pragma unroll
    for (int j = 0; j < 8; ++j) sw[j] = __shfl_xor(pk[j], 32, 64);

    union { unsigned u[4]; bf16x8 v; } b1;
    b1.u[0] = hf ? sw[2] : pk[0];
    b1.u[1] = hf ? sw[3] : pk[1];
    b1.u[2] = hf ? pk[2] : sw[0];
    b1.u[3] = hf ? pk[3] : sw[1];
    bf16x8 va1 = {};
    if (qc < 8) va1 = *(const bf16x8*)(Vs + qc*VSTR + k0l + 8*hf);
    oacc = __builtin_amdgcn_mfma_f32_32x32x16_bf16(va1, b1.v, oacc, 0, 0, 0);

    union { unsigned u[4]; bf16x8 v; } b2;
    b2.u[0] = hf ? sw[6] : pk[4];
    b2.u[1] = hf ? sw[7] : pk[5];
    b2.u[2] = hf ? pk[6] : sw[4];
    b2.u[3] = hf ? pk[7] : sw[5];
    bf16x8 va2 = {};
    if (qc < 8) va2 = *(const bf16x8*)(Vs + qc*VSTR + k0l + 16 + 8*hf);
    oacc = __builtin_amdgcn_mfma_f32_32x32x16_bf16(va2, b2.v, oacc, 0, 0, 0);
  }

  float lsum = lacc + __shfl_xor(lacc, 32, 64);
  float rcp = 1.f / lsum;
  unsigned short ov[4];
  #pragma unroll
  for (int j = 0; j < 4; ++j) ov[j] = (unsigned short)f2bf(oacc[j] * rcp);
  *(uint2*)(out + ((size_t)b*SB + qglob)*DM + hh*8 + 4*hf) = *(uint2*)ov;
}

// ---------- pool finalize + classifier ----------
__global__ __launch_bounds__(256) void pool_finalize(const float* __restrict__ part,
    const float* __restrict__ wcls, const float* __restrict__ bcls, float* __restrict__ out)
{
  int tid = threadIdx.x;
  int b = tid >> 6, d = tid & 63;
  float sum = 0.f;
  #pragma unroll 8
  for (int i = 0; i < 128; ++i) sum += part[(b*128 + i)*64 + d];
  __shared__ float pooled[4][64];
  pooled[b][d] = sum * (1.f/4096.f);
  __syncthreads();
  if (tid < 40) {
    int bb = tid / 10, c = tid % 10;
    float acc = bcls[c];
    #pragma unroll
    for (int dd = 0; dd < 64; ++dd) acc = fmaf(pooled[bb][dd], wcls[dd*10 + c], acc);
    out[tid] = acc;
  }
}

// ---------- launcher ----------
extern "C" void kernel_launch(void* const* d_in, const int* in_sizes, int n_in,
                              void* d_out, int out_size, void* d_ws, size_t ws_size,
                              hipStream_t stream)
{
  const int*   x    = (const int*)d_in[0];
  const float* emb  = (const float*)d_in[1];
  const float* wq   = (const float*)d_in[2];
  const float* bq   = (const float*)d_in[3];
  const float* wk   = (const float*)d_in[4];
  const float* bk   = (const float*)d_in[5];
  const float* wv   = (const float*)d_in[6];
  const float* bv   = (const float*)d_in[7];
  const float* wo   = (const float*)d_in[8];
  const float* bo   = (const float*)d_in[9];
  const float* ln1s = (const float*)d_in[10];
  const float* ln1b = (const float*)d_in[11];
  const float* ln2s = (const float*)d_in[12];
  const float* ln2b = (const float*)d_in[13];
  const float* w1   = (const float*)d_in[14];
  const float* b1   = (const float*)d_in[15];
  const float* w2   = (const float*)d_in[16];
  const float* b2   = (const float*)d_in[17];
  const float* lnfs = (const float*)d_in[18];
  const float* lnfb = (const float*)d_in[19];
  const float* wcls = (const float*)d_in[20];
  const float* bcls = (const float*)d_in[21];
  float* out = (float*)d_out;

  char* wsb = (char*)d_ws;
  const size_t MB = 1u << 20;
  float* h  = (float*)(wsb);                             // 4 MB f32 [16384][64]
  unsigned short* qb2 = (unsigned short*)(wsb + 4*MB);   // 2 MB bf16
  unsigned short* kb2 = (unsigned short*)(wsb + 6*MB);
  unsigned short* vb2 = (unsigned short*)(wsb + 8*MB);
  __hip_bfloat16* ab  = (__hip_bfloat16*)(wsb + 10*MB);  // 2 MB bf16
  short* wqT = (short*)(wsb + 12*MB);
  short* wkT = (short*)(wsb + 12*MB + 32*1024);
  short* wvT = (short*)(wsb + 12*MB + 64*1024);
  short* woT = (short*)(wsb + 12*MB + 96*1024);
  short* w1T = (short*)(wsb + 12*MB + 128*1024);         // 256 KB
  short* w2T = (short*)(wsb + 12*MB + 384*1024);         // 256 KB
  float* part = (float*)(wsb + 13*MB);                   // 128 KB

  wconv<<<dim3(80,4),256,0,stream>>>(wq,wk,wv,wo,w1,w2, wqT,wkT,wvT,woT,w1T,w2T);

  // head: embed + LN1(l0) + qkv(l0)
  fused_kernel<true,false><<<512,256,0,stream>>>(
      x, emb, nullptr,
      nullptr, nullptr, nullptr, nullptr,
      nullptr, nullptr, nullptr, nullptr,
      ln1s, ln1b,
      wqT, wkT, wvT, bq, bk, bv,
      qb2, kb2, vb2, h, nullptr);

  for (int l = 0; l < 4; ++l) {
    attn_kernel<<<dim3(32,32),256,0,stream>>>(qb2, kb2, vb2, ab);
    if (l < 3) {
      fused_kernel<false,false><<<512,256,0,stream>>>(
          nullptr, nullptr, (const unsigned short*)ab,
          woT+4096*l, bo+64*l, ln2s+64*l, ln2b+64*l,
          w1T+32768*l, b1+512*l, w2T+32768*l, b2+64*l,
          ln1s+64*(l+1), ln1b+64*(l+1),
          wqT+4096*(l+1), wkT+4096*(l+1), wvT+4096*(l+1),
          bq+64*(l+1), bk+64*(l+1), bv+64*(l+1),
          qb2, kb2, vb2, h, nullptr);
    } else {
      fused_kernel<false,true><<<512,256,0,stream>>>(
          nullptr, nullptr, (const unsigned short*)ab,
          woT+4096*l, bo+64*l, ln2s+64*l, ln2b+64*l,
          w1T+32768*l, b1+512*l, w2T+32768*l, b2+64*l,
          lnfs, lnfb,
          nullptr, nullptr, nullptr, nullptr, nullptr, nullptr,
          nullptr, nullptr, nullptr, h, part);
    }
  }
  pool_finalize<<<1,256,0,stream>>>(part, wcls, bcls, out);
}

// Round 7
// 228.900 us; speedup vs baseline: 3.8444x; 1.0997x over previous
//
#include <hip/hip_runtime.h>
#include <hip/hip_bf16.h>

#define DEV __device__ __forceinline__

typedef __attribute__((ext_vector_type(8))) short bf16x8;
typedef __attribute__((ext_vector_type(4))) float f32x4;
typedef __attribute__((ext_vector_type(16))) float f32x16;

// ---------- helpers ----------
DEV short f2bf(float x){ __hip_bfloat16 h = __float2bfloat16(x); return *(short*)&h; }
DEV unsigned pack2bf(float a, float b){
  return (unsigned)(unsigned short)f2bf(a) | ((unsigned)(unsigned short)f2bf(b) << 16);
}

// sigmoid-form tanh-GELU: x * sigmoid(2z), z = 0.7979(x + 0.0447 x^3)
DEV float gelu_fast(float x){
  float z = 0.7978845608028654f*(x + 0.044715f*x*x*x);
  float e = __expf(-2.f*z);
  return x / (1.f + e);
}

// dims
#define SB 4096
#define NT 16384   // B*S
#define DM 64

// ---------- weight convert+transpose: f32 [K][N] -> bf16 [N][K], 32x32 tiles ----------
__global__ __launch_bounds__(256) void wconv(
    const float* __restrict__ wq, const float* __restrict__ wk,
    const float* __restrict__ wv, const float* __restrict__ wo,
    const float* __restrict__ w1, const float* __restrict__ w2,
    short* __restrict__ wqT, short* __restrict__ wkT,
    short* __restrict__ wvT, short* __restrict__ woT,
    short* __restrict__ w1T, short* __restrict__ w2T)
{
  int t = blockIdx.x, l = blockIdx.y;
  const float* src; short* dst; int K, N, kt, nt;
  if (t < 16) {
    int m = t >> 2, sub = t & 3; kt = sub >> 1; nt = sub & 1; K = 64; N = 64;
    const float* s4[4] = {wq, wk, wv, wo};
    short*       d4[4] = {wqT, wkT, wvT, woT};
    src = s4[m] + l*4096; dst = d4[m] + l*4096;
  } else if (t < 48) {
    kt = (t-16) >> 4; nt = (t-16) & 15; K = 64; N = 512;
    src = w1 + l*32768; dst = w1T + l*32768;
  } else {
    kt = (t-48) >> 1; nt = (t-48) & 1; K = 512; N = 64;
    src = w2 + l*32768; dst = w2T + l*32768;
  }
  __shared__ float lds[32][33];
  int tx = threadIdx.x & 31, ty = threadIdx.x >> 5;
  int k0 = kt*32, n0 = nt*32;
  #pragma unroll
  for (int j=0;j<4;++j) lds[ty+8*j][tx] = src[(size_t)(k0+ty+8*j)*N + n0 + tx];
  __syncthreads();
  #pragma unroll
  for (int j=0;j<4;++j) {
    int nn = ty+8*j;
    dst[(size_t)(n0+nn)*K + k0 + tx] = f2bf(lds[tx][nn]);
  }
}

// ---------- fused building blocks ----------
DEV void make_frags_ln(const float* rowp, float mean, float inv,
    const float* __restrict__ s, const float* __restrict__ b, int kq,
    bf16x8& a0, bf16x8& a1){
  #pragma unroll
  for (int i=0;i<8;++i) a0[i] = f2bf((rowp[kq*8+i]-mean)*inv*s[kq*8+i]+b[kq*8+i]);
  #pragma unroll
  for (int i=0;i<8;++i) a1[i] = f2bf((rowp[32+kq*8+i]-mean)*inv*s[32+kq*8+i]+b[32+kq*8+i]);
}
// wave GEMM: 16 rows x 32 cols, K=64, B from bf16 [N][KS] transposed weights.
template<int KS>
DEV void gemm2(const bf16x8& a0, const bf16x8& a1, const short* __restrict__ WT,
               int cc0, int kq, int r, f32x4* acc){
  #pragma unroll
  for (int ct=0; ct<2; ++ct){
    const short* wp = WT + (size_t)(cc0 + ct*16 + r)*KS + kq*8;
    bf16x8 b0 = *(const bf16x8*)(wp);
    bf16x8 b1v = *(const bf16x8*)(wp + 32);
    acc[ct] = __builtin_amdgcn_mfma_f32_16x16x32_bf16(a0, b0,  acc[ct], 0, 0, 0);
    acc[ct] = __builtin_amdgcn_mfma_f32_16x16x32_bf16(a1, b1v, acc[ct], 0, 0, 0);
  }
}

// ---------- fused layer kernel v2 (wave-parallel FFN) ----------
// 32 rows/block, grid 512, 4 waves.
// attnout+res -> LN2 -> fc1 (wave w: cols 128w..128w+127, all 32 rows) -> mid(LDS bf16)
//   -> fc2 (wave quadrant 16x32, full K=512) +res -> LN1next+qkv | LNf+pool.
template<bool EMBED, bool LAST>
__global__ __launch_bounds__(256,2) void fused_kernel(
    const int* __restrict__ x, const float* __restrict__ emb,
    const unsigned short* __restrict__ ab,
    const short* __restrict__ woT, const float* __restrict__ bo,
    const float* __restrict__ ln2s, const float* __restrict__ ln2b,
    const short* __restrict__ w1T, const float* __restrict__ b1,
    const short* __restrict__ w2T, const float* __restrict__ b2,
    const float* __restrict__ lns, const float* __restrict__ lnb,   // LN1(next) or LNf
    const short* __restrict__ wqT, const short* __restrict__ wkT, const short* __restrict__ wvT,
    const float* __restrict__ bq, const float* __restrict__ bk, const float* __restrict__ bv,
    unsigned short* __restrict__ qo, unsigned short* __restrict__ ko, unsigned short* __restrict__ vo,
    float* __restrict__ h, float* __restrict__ part)
{
  __shared__ float hN[32][76];
  __shared__ short mid[32][520];
  __shared__ float mu[32], iv[32];

  const int bid = blockIdx.x;
  const int row_g0 = bid * 32;
  const int tid = threadIdx.x;
  const int w = tid >> 6, lane = tid & 63;
  const int r = lane & 15, kq = lane >> 4;
  const int wr0 = (w >> 1) * 16;
  const int cc0 = (w & 1) * 32;
  const int srow = tid >> 3, sdq = tid & 7;   // stats/embed mapping: 8 threads/row

  if constexpr (EMBED) {
    int tg = row_g0 + srow;
    int s = tg & (SB-1);
    int tok = x[tg];
    #pragma unroll
    for (int i=0;i<8;++i) {
      int d = sdq*8 + i;
      float fe = (float)(d & ~1) * (1.0f/64.0f);
      float invk = __expf(-9.210340371976184f * fe);
      float ang = (float)s * invk;
      float pe = (d & 1) ? __cosf(ang) : __sinf(ang);
      float val = emb[tok*DM + d] + pe;
      hN[srow][d] = val;
      h[(size_t)tg*DM + d] = val;
    }
  } else {
    // attn-out projection + residual
    const short* abp = (const short*)(ab + (size_t)(row_g0 + wr0 + r)*DM + kq*8);
    bf16x8 a0 = *(const bf16x8*)abp;
    bf16x8 a1 = *(const bf16x8*)(abp + 32);
    f32x4 acc[2] = {(f32x4){0,0,0,0},(f32x4){0,0,0,0}};
    gemm2<64>(a0, a1, woT, cc0, kq, r, acc);
    #pragma unroll
    for (int ct=0; ct<2; ++ct) {
      int col = cc0 + ct*16 + r;
      #pragma unroll
      for (int j=0;j<4;++j) {
        int rl = wr0 + kq*4 + j;
        hN[rl][col] = acc[ct][j] + bo[col] + h[(size_t)(row_g0+rl)*DM + col];
      }
    }
  }
  __syncthreads();

  // LN stats (LN1 for EMBED, LN2 otherwise)
  {
    const float* p = &hN[srow][sdq*8];
    float v[8];
    #pragma unroll
    for (int i=0;i<8;++i) v[i] = p[i];
    float sum = 0.f;
    #pragma unroll
    for (int i=0;i<8;++i) sum += v[i];
    sum += __shfl_xor(sum, 1, 64); sum += __shfl_xor(sum, 2, 64); sum += __shfl_xor(sum, 4, 64);
    float mean = sum * (1.f/64.f);
    float sq = 0.f;
    #pragma unroll
    for (int i=0;i<8;++i) { float d = v[i]-mean; sq += d*d; }
    sq += __shfl_xor(sq, 1, 64); sq += __shfl_xor(sq, 2, 64); sq += __shfl_xor(sq, 4, 64);
    if (sdq == 0) { mu[srow] = mean; iv[srow] = rsqrtf(sq*(1.f/64.f) + 1e-6f); }
  }
  __syncthreads();

  if constexpr (!EMBED) {
    // ---- fc1: wave w covers cols [128w, 128w+128), rows 0..31 ----
    bf16x8 a00, a01, a10, a11;
    make_frags_ln(&hN[r][0],    mu[r],    iv[r],    ln2s, ln2b, kq, a00, a01);
    make_frags_ln(&hN[16+r][0], mu[16+r], iv[16+r], ln2s, ln2b, kq, a10, a11);
    f32x4 acc1[2][8];
    #pragma unroll
    for (int rh=0; rh<2; ++rh)
      #pragma unroll
      for (int ct=0; ct<8; ++ct) acc1[rh][ct] = (f32x4){0.f,0.f,0.f,0.f};
    #pragma unroll
    for (int ct=0; ct<8; ++ct) {
      const short* wp = w1T + (size_t)(w*128 + ct*16 + r)*64 + kq*8;
      bf16x8 b0  = *(const bf16x8*)(wp);
      bf16x8 b1v = *(const bf16x8*)(wp + 32);
      acc1[0][ct] = __builtin_amdgcn_mfma_f32_16x16x32_bf16(a00, b0,  acc1[0][ct], 0, 0, 0);
      acc1[0][ct] = __builtin_amdgcn_mfma_f32_16x16x32_bf16(a01, b1v, acc1[0][ct], 0, 0, 0);
      acc1[1][ct] = __builtin_amdgcn_mfma_f32_16x16x32_bf16(a10, b0,  acc1[1][ct], 0, 0, 0);
      acc1[1][ct] = __builtin_amdgcn_mfma_f32_16x16x32_bf16(a11, b1v, acc1[1][ct], 0, 0, 0);
    }
    #pragma unroll
    for (int ct=0; ct<8; ++ct) {
      int col = w*128 + ct*16 + r;
      float bb = b1[col];
      #pragma unroll
      for (int rh=0; rh<2; ++rh)
        #pragma unroll
        for (int j=0; j<4; ++j)
          mid[rh*16 + kq*4 + j][col] = f2bf(gelu_fast(acc1[rh][ct][j] + bb));
    }
    __syncthreads();

    // ---- fc2: wave quadrant (wr0, cc0), K=512 ----
    f32x4 acc2[2] = {(f32x4){0,0,0,0},(f32x4){0,0,0,0}};
    #pragma unroll
    for (int ks=0; ks<16; ++ks) {
      bf16x8 af = *(const bf16x8*)(&mid[wr0 + r][ks*32 + kq*8]);
      const short* wp = w2T + (size_t)(cc0 + r)*512 + ks*32 + kq*8;
      bf16x8 b0  = *(const bf16x8*)(wp);
      bf16x8 b1v = *(const bf16x8*)(wp + (size_t)16*512);
      acc2[0] = __builtin_amdgcn_mfma_f32_16x16x32_bf16(af, b0,  acc2[0], 0, 0, 0);
      acc2[1] = __builtin_amdgcn_mfma_f32_16x16x32_bf16(af, b1v, acc2[1], 0, 0, 0);
    }
    #pragma unroll
    for (int ct=0; ct<2; ++ct) {
      int col = cc0 + ct*16 + r;
      float bb = b2[col];
      #pragma unroll
      for (int j=0; j<4; ++j) {
        int rl = wr0 + kq*4 + j;
        float val = acc2[ct][j] + bb + hN[rl][col];
        hN[rl][col] = val;
        h[(size_t)(row_g0+rl)*DM + col] = val;
      }
    }
    __syncthreads();

    // LN stats for LN1(next) / LNf
    {
      const float* p = &hN[srow][sdq*8];
      float v[8];
      #pragma unroll
      for (int i=0;i<8;++i) v[i] = p[i];
      float sum = 0.f;
      #pragma unroll
      for (int i=0;i<8;++i) sum += v[i];
      sum += __shfl_xor(sum, 1, 64); sum += __shfl_xor(sum, 2, 64); sum += __shfl_xor(sum, 4, 64);
      float mean = sum * (1.f/64.f);
      float sq = 0.f;
      #pragma unroll
      for (int i=0;i<8;++i) { float d = v[i]-mean; sq += d*d; }
      sq += __shfl_xor(sq, 1, 64); sq += __shfl_xor(sq, 2, 64); sq += __shfl_xor(sq, 4, 64);
      if (sdq == 0) { mu[srow] = mean; iv[srow] = rsqrtf(sq*(1.f/64.f) + 1e-6f); }
    }
    __syncthreads();
  }

  if constexpr (!LAST) {
    // qkv of (next) layer
    const float qscale = 0.35355339059327373f;  // 1/sqrt(8)
    bf16x8 a0, a1;
    make_frags_ln(&hN[wr0+r][0], mu[wr0+r], iv[wr0+r], lns, lnb, kq, a0, a1);
    f32x4 aq[2] = {(f32x4){0,0,0,0},(f32x4){0,0,0,0}};
    f32x4 akk[2] = {(f32x4){0,0,0,0},(f32x4){0,0,0,0}};
    f32x4 av[2] = {(f32x4){0,0,0,0},(f32x4){0,0,0,0}};
    gemm2<64>(a0, a1, wqT, cc0, kq, r, aq);
    gemm2<64>(a0, a1, wkT, cc0, kq, r, akk);
    gemm2<64>(a0, a1, wvT, cc0, kq, r, av);
    #pragma unroll
    for (int ct=0; ct<2; ++ct) {
      int col = cc0 + ct*16 + r;
      float bqv = bq[col], bkv = bk[col], bvv = bv[col];
      #pragma unroll
      for (int j=0;j<4;++j) {
        size_t oi = (size_t)(row_g0 + wr0 + kq*4 + j)*DM + col;
        qo[oi] = (unsigned short)f2bf((aq[ct][j] + bqv)*qscale);
        ko[oi] = (unsigned short)f2bf(akk[ct][j] + bkv);
        vo[oi] = (unsigned short)f2bf(av[ct][j] + bvv);
      }
    }
  } else {
    // final LN (in place) + pool partial (sum of 32 rows per dim)
    float mean = mu[srow], inv = iv[srow];
    #pragma unroll
    for (int i=0;i<8;++i) {
      int d = sdq*8 + i;
      hN[srow][d] = (hN[srow][d]-mean)*inv*lns[d] + lnb[d];
    }
    __syncthreads();
    if (tid < 64) {
      float s = 0.f;
      #pragma unroll 4
      for (int rr=0; rr<32; ++rr) s += hN[rr][tid];
      part[bid*64 + tid] = s;
    }
  }
}

// ---------- sliding-window attention (MFMA) ----------
#define VSTR 664
__global__ __launch_bounds__(256) void attn_kernel(
    const unsigned short* __restrict__ qg_,
    const unsigned short* __restrict__ kg_,
    const unsigned short* __restrict__ vg_,
    __hip_bfloat16* __restrict__ out)
{
  const int qblk = blockIdx.x, bh = blockIdx.y;
  const int b = bh >> 3, hh = bh & 7;
  const int tid = threadIdx.x;
  const int q0b = qblk << 7;
  const int kbase = q0b - 256;

  __shared__ unsigned short Ks[640*8];
  __shared__ unsigned short Vs[8*VSTR];

  const unsigned short* kgp = kg_ + ((size_t)b*SB)*DM + hh*8;
  const unsigned short* vgp = vg_ + ((size_t)b*SB)*DM + hh*8;

  for (int e = tid; e < 640; e += 256) {
    int g = kbase + e;
    uint4 kv = make_uint4(0,0,0,0), vv = make_uint4(0,0,0,0);
    if ((unsigned)g < (unsigned)SB) {
      kv = *(const uint4*)(kgp + (size_t)g*DM);
      vv = *(const uint4*)(vgp + (size_t)g*DM);
    }
    *(uint4*)(Ks + e*8) = kv;
    const unsigned short* pv = (const unsigned short*)&vv;
    #pragma unroll
    for (int d = 0; d < 8; ++d) Vs[d*VSTR + e] = pv[d];
  }
  __syncthreads();

  const int w = tid >> 6;
  const int lane = tid & 63;
  const int qc = lane & 31;
  const int hf = lane >> 5;
  const int qglob = q0b + 32*w + qc;

  bf16x8 qfrag = {};
  if (hf == 0) qfrag = *(const bf16x8*)(qg_ + ((size_t)b*SB + qglob)*DM + hh*8);

  f32x16 oacc = {};
  float lacc = 0.f;

  for (int t = 0; t <= 16; ++t) {
    const int k0l = 32*w + 32*t;
    const int k0g = kbase + k0l;
    if (k0g > SB-1 || k0g + 31 < 0) continue;

    bf16x8 kfrag = {};
    if (hf == 0) kfrag = *(const bf16x8*)(Ks + (k0l + qc)*8);

    f32x16 s = __builtin_amdgcn_mfma_f32_32x32x16_bf16(kfrag, qfrag, (f32x16){}, 0, 0, 0);

    float p[16];
    bool needmask = (t == 0) | (t == 16) | (k0g < 0) | (k0g + 31 > SB-1);
    if (needmask) {
      #pragma unroll
      for (int rr = 0; rr < 16; ++rr) {
        int klg = k0g + (rr&3) + 8*(rr>>2) + 4*hf;
        bool ok = ((unsigned)(klg - qglob + 256) <= 512u) && ((unsigned)klg < (unsigned)SB);
        p[rr] = ok ? __expf(s[rr]) : 0.f;
      }
    } else {
      #pragma unroll
      for (int rr = 0; rr < 16; ++rr) p[rr] = __expf(s[rr]);
    }
    #pragma unroll
    for (int rr = 0; rr < 16; ++rr) lacc += p[rr];

    unsigned pk[8];
    #pragma unroll
    for (int j = 0; j < 8; ++j) pk[j] = pack2bf(p[2*j], p[2*j+1]);
    unsigned sw[8];
    #pragma unroll
    for (int j = 0; j < 8; ++j) sw[j] = __shfl_xor(pk[j], 32, 64);

    union { unsigned u[4]; bf16x8 v; } b1;
    b1.u[0] = hf ? sw[2] : pk[0];
    b1.u[1] = hf ? sw[3] : pk[1];
    b1.u[2] = hf ? pk[2] : sw[0];
    b1.u[3] = hf ? pk[3] : sw[1];
    bf16x8 va1 = {};
    if (qc < 8) va1 = *(const bf16x8*)(Vs + qc*VSTR + k0l + 8*hf);
    oacc = __builtin_amdgcn_mfma_f32_32x32x16_bf16(va1, b1.v, oacc, 0, 0, 0);

    union { unsigned u[4]; bf16x8 v; } b2;
    b2.u[0] = hf ? sw[6] : pk[4];
    b2.u[1] = hf ? sw[7] : pk[5];
    b2.u[2] = hf ? pk[6] : sw[4];
    b2.u[3] = hf ? pk[7] : sw[5];
    bf16x8 va2 = {};
    if (qc < 8) va2 = *(const bf16x8*)(Vs + qc*VSTR + k0l + 16 + 8*hf);
    oacc = __builtin_amdgcn_mfma_f32_32x32x16_bf16(va2, b2.v, oacc, 0, 0, 0);
  }

  float lsum = lacc + __shfl_xor(lacc, 32, 64);
  float rcp = 1.f / lsum;
  unsigned short ov[4];
  #pragma unroll
  for (int j = 0; j < 4; ++j) ov[j] = (unsigned short)f2bf(oacc[j] * rcp);
  *(uint2*)(out + ((size_t)b*SB + qglob)*DM + hh*8 + 4*hf) = *(uint2*)ov;
}

// ---------- pool finalize + classifier ----------
__global__ __launch_bounds__(256) void pool_finalize(const float* __restrict__ part,
    const float* __restrict__ wcls, const float* __restrict__ bcls, float* __restrict__ out)
{
  int tid = threadIdx.x;
  int b = tid >> 6, d = tid & 63;
  float sum = 0.f;
  #pragma unroll 8
  for (int i = 0; i < 128; ++i) sum += part[(b*128 + i)*64 + d];
  __shared__ float pooled[4][64];
  pooled[b][d] = sum * (1.f/4096.f);
  __syncthreads();
  if (tid < 40) {
    int bb = tid / 10, c = tid % 10;
    float acc = bcls[c];
    #pragma unroll
    for (int dd = 0; dd < 64; ++dd) acc = fmaf(pooled[bb][dd], wcls[dd*10 + c], acc);
    out[tid] = acc;
  }
}

// ---------- launcher ----------
extern "C" void kernel_launch(void* const* d_in, const int* in_sizes, int n_in,
                              void* d_out, int out_size, void* d_ws, size_t ws_size,
                              hipStream_t stream)
{
  const int*   x    = (const int*)d_in[0];
  const float* emb  = (const float*)d_in[1];
  const float* wq   = (const float*)d_in[2];
  const float* bq   = (const float*)d_in[3];
  const float* wk   = (const float*)d_in[4];
  const float* bk   = (const float*)d_in[5];
  const float* wv   = (const float*)d_in[6];
  const float* bv   = (const float*)d_in[7];
  const float* wo   = (const float*)d_in[8];
  const float* bo   = (const float*)d_in[9];
  const float* ln1s = (const float*)d_in[10];
  const float* ln1b = (const float*)d_in[11];
  const float* ln2s = (const float*)d_in[12];
  const float* ln2b = (const float*)d_in[13];
  const float* w1   = (const float*)d_in[14];
  const float* b1   = (const float*)d_in[15];
  const float* w2   = (const float*)d_in[16];
  const float* b2   = (const float*)d_in[17];
  const float* lnfs = (const float*)d_in[18];
  const float* lnfb = (const float*)d_in[19];
  const float* wcls = (const float*)d_in[20];
  const float* bcls = (const float*)d_in[21];
  float* out = (float*)d_out;

  char* wsb = (char*)d_ws;
  const size_t MB = 1u << 20;
  float* h  = (float*)(wsb);                             // 4 MB f32 [16384][64]
  unsigned short* qb2 = (unsigned short*)(wsb + 4*MB);   // 2 MB bf16
  unsigned short* kb2 = (unsigned short*)(wsb + 6*MB);
  unsigned short* vb2 = (unsigned short*)(wsb + 8*MB);
  __hip_bfloat16* ab  = (__hip_bfloat16*)(wsb + 10*MB);  // 2 MB bf16
  short* wqT = (short*)(wsb + 12*MB);
  short* wkT = (short*)(wsb + 12*MB + 32*1024);
  short* wvT = (short*)(wsb + 12*MB + 64*1024);
  short* woT = (short*)(wsb + 12*MB + 96*1024);
  short* w1T = (short*)(wsb + 12*MB + 128*1024);         // 256 KB
  short* w2T = (short*)(wsb + 12*MB + 384*1024);         // 256 KB
  float* part = (float*)(wsb + 13*MB);                   // 128 KB

  wconv<<<dim3(80,4),256,0,stream>>>(wq,wk,wv,wo,w1,w2, wqT,wkT,wvT,woT,w1T,w2T);

  // head: embed + LN1(l0) + qkv(l0)
  fused_kernel<true,false><<<512,256,0,stream>>>(
      x, emb, nullptr,
      nullptr, nullptr, nullptr, nullptr,
      nullptr, nullptr, nullptr, nullptr,
      ln1s, ln1b,
      wqT, wkT, wvT, bq, bk, bv,
      qb2, kb2, vb2, h, nullptr);

  for (int l = 0; l < 4; ++l) {
    attn_kernel<<<dim3(32,32),256,0,stream>>>(qb2, kb2, vb2, ab);
    if (l < 3) {
      fused_kernel<false,false><<<512,256,0,stream>>>(
          nullptr, nullptr, (const unsigned short*)ab,
          woT+4096*l, bo+64*l, ln2s+64*l, ln2b+64*l,
          w1T+32768*l, b1+512*l, w2T+32768*l, b2+64*l,
          ln1s+64*(l+1), ln1b+64*(l+1),
          wqT+4096*(l+1), wkT+4096*(l+1), wvT+4096*(l+1),
          bq+64*(l+1), bk+64*(l+1), bv+64*(l+1),
          qb2, kb2, vb2, h, nullptr);
    } else {
      fused_kernel<false,true><<<512,256,0,stream>>>(
          nullptr, nullptr, (const unsigned short*)ab,
          woT+4096*l, bo+64*l, ln2s+64*l, ln2b+64*l,
          w1T+32768*l, b1+512*l, w2T+32768*l, b2+64*l,
          lnfs, lnfb,
          nullptr, nullptr, nullptr, nullptr, nullptr, nullptr,
          nullptr, nullptr, nullptr, h, part);
    }
  }
  pool_finalize<<<1,256,0,stream>>>(part, wcls, bcls, out);
}